// Round 6
// baseline (964.471 us; speedup 1.0000x reference)
//
#include <hip/hip_runtime.h>

typedef _Float16 f16;
typedef _Float16 f16x8 __attribute__((ext_vector_type(8)));
typedef _Float16 f16x4 __attribute__((ext_vector_type(4)));
typedef float    f32x16 __attribute__((ext_vector_type(16)));

#define GLDS(gp, lp) __builtin_amdgcn_global_load_lds( \
    (const __attribute__((address_space(1))) void*)(gp), \
    (__attribute__((address_space(3))) void*)(lp), 16, 0, 0)

// ---------------------------------------------------------------------------
// 256x256 tile, BK=64, **256 threads = 4 waves (2M x 2N), 128x128 per wave**.
// Rationale: the 8-wave variant was LDS-read-bound (192 KB ds_read per K-tile
// per CU = 4x A amplification; MFMA demand only ~576 cyc/tile).  128x128
// waves cut LDS reads to 128 KB/tile (each operand read by 2 waves, not 4/2).
// acc = 4x4 f32x16 = 256 VGPR -> 1 wave/SIMD; acceptable because the binding
// constraint is LDS queue THROUGHPUT (reads pipeline per-CU), not latency.
// Same 8-phase K-loop skeleton, counted vmcnt gates (x2 calls -> vmcnt(12)).
// Region liveness (32-row GLDS granularity, phases mi0..mi3 per buf):
//   A-head {0,32,128,160} dies mi1; A-tail {64,96,192,224} dies mi3;
//   B (all) dies mi0.  Schedule below keeps >=1 barrier between last read
//   and the GLDS overwrite of every region (same guarantee as proven R2/R5).
// ---------------------------------------------------------------------------
template<typename OUT_T, bool BIAS, bool RELU>
__global__ __launch_bounds__(256, 1)
void gemm_bt2(const f16* __restrict__ A, const f16* __restrict__ Bm,
              OUT_T* __restrict__ C, const float* __restrict__ bias,
              int M, int N, int K, long sA, long sB, long sC)
{
    constexpr int TSZ = 256 * 64;          // f16 elements per tile buffer
    __shared__ alignas(16) f16 As[2 * TSZ];
    __shared__ alignas(16) f16 Bs[2 * TSZ];

    int bx = blockIdx.x, by = blockIdx.y;
    {   // XCD-locality remap (gy % 8 == 0 for all uses)
        const int gx = gridDim.x;
        const int l = by * gx + bx;
        const int W = gx * 8;
        const int ygrp = l / W;
        const int rem = l - ygrp * W;
        bx = rem >> 3;
        by = ygrp * 8 + (rem & 7);
    }
    const int z = blockIdx.z;
    A  += (long)z * sA;
    Bm += (long)z * sB;
    C  += (long)z * sC;

    const int tid  = threadIdx.x;
    const int wid  = tid >> 6;             // 0..3
    const int lane = tid & 63;
    const int lr = lane & 31;
    const int lh = lane >> 5;
    const int m0 = by * 256;
    const int n0 = bx * 256;
    const int wm = (wid >> 1) * 128;       // wave row: 0 or 128
    const int wn = (wid & 1) * 128;        // wave col: 0 or 128

    // staging: one GLDS call covers 32 rows (8 rows/wave, 8 x 16B slots/row).
    // LDS row r slot s holds source k-segment (s ^ (r&7))  [XOR swizzle]
    const int sr = tid >> 3;                         // row 0..31 within call
    const int sg = ((tid & 7) ^ (sr & 7)) * 8;       // pre-swizzled source col
    const f16* agS = A  + (long)(m0 + sr) * K + sg;
    const f16* bgS = Bm + (long)(n0 + sr) * K + sg;
    f16* aD = As + wid * (8 * 64);                   // wave-uniform LDS base
    f16* bD = Bs + wid * (8 * 64);

    // fragment read: k-segment g = 2*ks + lh at slot g ^ (row&7)
    const int s7  = lr & 7;
    const int xs0 = ((0 + lh) ^ s7) * 8;
    const int xs1 = ((2 + lh) ^ s7) * 8;
    const int xs2 = ((4 + lh) ^ s7) * 8;
    const int xs3 = ((6 + lh) ^ s7) * 8;
    const f16* aR = As + (wm + lr) * 64;
    const f16* bR = Bs + (wn + lr) * 64;

    f32x16 acc[4][4];
#pragma unroll
    for (int mi = 0; mi < 4; ++mi)
#pragma unroll
        for (int ni = 0; ni < 4; ++ni)
#pragma unroll
            for (int r = 0; r < 16; ++r) acc[mi][ni][r] = 0.f;

    // B fragments: nj (0..3) x ks (0..3), held in regs across a buf window
    f16x8 b00, b01, b02, b03, b10, b11, b12, b13;
    f16x8 b20, b21, b22, b23, b30, b31, b32, b33;

    const int NT = K >> 6;

#define GA2(buf, R0, kt) GLDS(agS + (long)(R0) * K + (kt), aD + (buf) * TSZ + (R0) * 64)
#define GB2(buf, R0, kt) GLDS(bgS + (long)(R0) * K + (kt), bD + (buf) * TSZ + (R0) * 64)
#define AHEAD(buf, kt) GA2(buf,   0, kt); GA2(buf,  32, kt); GA2(buf, 128, kt); GA2(buf, 160, kt);
#define ATAIL(buf, kt) GA2(buf,  64, kt); GA2(buf,  96, kt); GA2(buf, 192, kt); GA2(buf, 224, kt);
#define BHA(buf, kt)   GB2(buf,   0, kt); GB2(buf,  32, kt); GB2(buf,  64, kt); GB2(buf,  96, kt);
#define BHB(buf, kt)   GB2(buf, 128, kt); GB2(buf, 160, kt); GB2(buf, 192, kt); GB2(buf, 224, kt);

    // prologue: buf0 complete (16 oldest), then B1 (8) + A1-head (4).
    // vmcnt(12) forces the oldest 16 (= all of buf0) landed.
    BHA(0, 0)  BHB(0, 0)  AHEAD(0, 0)  ATAIL(0, 0)
    BHA(1, 64) BHB(1, 64) AHEAD(1, 64)
    asm volatile("s_waitcnt vmcnt(12)" ::: "memory");
    __builtin_amdgcn_s_barrier();

#define BFREAD(buf) \
    b00 = *(const f16x8*)(bR + (buf) * TSZ +    0 + xs0); \
    b01 = *(const f16x8*)(bR + (buf) * TSZ +    0 + xs1); \
    b02 = *(const f16x8*)(bR + (buf) * TSZ +    0 + xs2); \
    b03 = *(const f16x8*)(bR + (buf) * TSZ +    0 + xs3); \
    b10 = *(const f16x8*)(bR + (buf) * TSZ + 2048 + xs0); \
    b11 = *(const f16x8*)(bR + (buf) * TSZ + 2048 + xs1); \
    b12 = *(const f16x8*)(bR + (buf) * TSZ + 2048 + xs2); \
    b13 = *(const f16x8*)(bR + (buf) * TSZ + 2048 + xs3); \
    b20 = *(const f16x8*)(bR + (buf) * TSZ + 4096 + xs0); \
    b21 = *(const f16x8*)(bR + (buf) * TSZ + 4096 + xs1); \
    b22 = *(const f16x8*)(bR + (buf) * TSZ + 4096 + xs2); \
    b23 = *(const f16x8*)(bR + (buf) * TSZ + 4096 + xs3); \
    b30 = *(const f16x8*)(bR + (buf) * TSZ + 6144 + xs0); \
    b31 = *(const f16x8*)(bR + (buf) * TSZ + 6144 + xs1); \
    b32 = *(const f16x8*)(bR + (buf) * TSZ + 6144 + xs2); \
    b33 = *(const f16x8*)(bR + (buf) * TSZ + 6144 + xs3);

// 16 MFMA: ks-outer, nj-inner -> consecutive MFMAs hit different acc
// (4 interleaved dependent chains of length 4: latency self-hidden).
#define MFMA16(mi) \
    acc[mi][0] = __builtin_amdgcn_mfma_f32_32x32x16_f16(af0, b00, acc[mi][0], 0, 0, 0); \
    acc[mi][1] = __builtin_amdgcn_mfma_f32_32x32x16_f16(af0, b10, acc[mi][1], 0, 0, 0); \
    acc[mi][2] = __builtin_amdgcn_mfma_f32_32x32x16_f16(af0, b20, acc[mi][2], 0, 0, 0); \
    acc[mi][3] = __builtin_amdgcn_mfma_f32_32x32x16_f16(af0, b30, acc[mi][3], 0, 0, 0); \
    acc[mi][0] = __builtin_amdgcn_mfma_f32_32x32x16_f16(af1, b01, acc[mi][0], 0, 0, 0); \
    acc[mi][1] = __builtin_amdgcn_mfma_f32_32x32x16_f16(af1, b11, acc[mi][1], 0, 0, 0); \
    acc[mi][2] = __builtin_amdgcn_mfma_f32_32x32x16_f16(af1, b21, acc[mi][2], 0, 0, 0); \
    acc[mi][3] = __builtin_amdgcn_mfma_f32_32x32x16_f16(af1, b31, acc[mi][3], 0, 0, 0); \
    acc[mi][0] = __builtin_amdgcn_mfma_f32_32x32x16_f16(af2, b02, acc[mi][0], 0, 0, 0); \
    acc[mi][1] = __builtin_amdgcn_mfma_f32_32x32x16_f16(af2, b12, acc[mi][1], 0, 0, 0); \
    acc[mi][2] = __builtin_amdgcn_mfma_f32_32x32x16_f16(af2, b22, acc[mi][2], 0, 0, 0); \
    acc[mi][3] = __builtin_amdgcn_mfma_f32_32x32x16_f16(af2, b32, acc[mi][3], 0, 0, 0); \
    acc[mi][0] = __builtin_amdgcn_mfma_f32_32x32x16_f16(af3, b03, acc[mi][0], 0, 0, 0); \
    acc[mi][1] = __builtin_amdgcn_mfma_f32_32x32x16_f16(af3, b13, acc[mi][1], 0, 0, 0); \
    acc[mi][2] = __builtin_amdgcn_mfma_f32_32x32x16_f16(af3, b23, acc[mi][2], 0, 0, 0); \
    acc[mi][3] = __builtin_amdgcn_mfma_f32_32x32x16_f16(af3, b33, acc[mi][3], 0, 0, 0);

// Phase: 4 A ds_reads [+16 B ds_reads at mi0] | 4 GLDS | barrier |
//        16 MFMA (progressive lgkm) | [vmcnt(12)] | barrier
#define PH(buf, mi, RB, VW, ...) { \
    f16x8 af0 = *(const f16x8*)(aR + (buf) * TSZ + (mi) * 2048 + xs0); \
    f16x8 af1 = *(const f16x8*)(aR + (buf) * TSZ + (mi) * 2048 + xs1); \
    f16x8 af2 = *(const f16x8*)(aR + (buf) * TSZ + (mi) * 2048 + xs2); \
    f16x8 af3 = *(const f16x8*)(aR + (buf) * TSZ + (mi) * 2048 + xs3); \
    if (RB) { BFREAD(buf) } \
    __VA_ARGS__ \
    __builtin_amdgcn_s_barrier(); \
    __builtin_amdgcn_s_setprio(1); \
    MFMA16(mi) \
    __builtin_amdgcn_s_setprio(0); \
    if (VW) { asm volatile("s_waitcnt vmcnt(12)" ::: "memory"); } \
    __builtin_amdgcn_s_barrier(); \
}

    for (int i = 0; i < NT / 2; ++i) {
        const long k1 = (long)(2 * i + 1) << 6;                           // tile t+1
        const long kA = (2 * i + 2 < NT) ? ((long)(2 * i + 2) << 6) : 0;  // tile t+2
        const long kB = (2 * i + 3 < NT) ? ((long)(2 * i + 3) << 6) : 0;  // tile t+3
        // gate at P3: newest 12 = P1+P2+P3 -> forces A1-tail(P0)+A1-head(P7')
        //             + B1 (prev iter) landed => buf1 complete before P4.
        // gate at P7: newest 12 = P5+P6+P7 -> forces A0(P3,P4)+B0(P1,P2)
        //             landed => buf0 (t+2) complete before next P0.
        PH(0, 0, 1, 0, ATAIL(1, k1))
        PH(0, 1, 0, 0, BHA(0, kA))
        PH(0, 2, 0, 0, BHB(0, kA))
        PH(0, 3, 0, 1, AHEAD(0, kA))
        PH(1, 0, 1, 0, ATAIL(0, kA))
        PH(1, 1, 0, 0, BHA(1, kB))
        PH(1, 2, 0, 0, BHB(1, kB))
        PH(1, 3, 0, 1, AHEAD(1, kB))
    }

    asm volatile("s_waitcnt vmcnt(0)" ::: "memory");    // drain before LDS dealloc

    // C/D layout (32x32): col = lane&31, row = (reg&3) + 8*(reg>>2) + 4*(lane>>5)
#pragma unroll
    for (int ni = 0; ni < 4; ++ni) {
        const int gc = n0 + wn + ni * 32 + lr;
        const float bv = BIAS ? bias[gc] : 0.0f;
#pragma unroll
        for (int mi = 0; mi < 4; ++mi) {
#pragma unroll
            for (int r = 0; r < 16; ++r) {
                const int row = (r & 3) + 8 * (r >> 2) + 4 * lh;
                const int gr = m0 + wm + mi * 32 + row;
                float v = acc[mi][ni][r] + bv;
                if (RELU) v = fmaxf(v, 0.0f);
                C[(long)gr * N + gc] = (OUT_T)v;
            }
        }
    }
#undef PH
#undef MFMA16
#undef BFREAD
#undef AHEAD
#undef ATAIL
#undef BHA
#undef BHB
#undef GA2
#undef GB2
}

// ---------------------------------------------------------------------------
// 256x128 tile, BK=64, 512 threads (8 waves 4M x 2N, 64x64 per wave),
// 4-phase K-loop, B through LDS.  LDS 96 KiB, XOR-swizzled.  (Proven R5 form,
// unchanged — used for G3 where a 256x256 grid would underfill CUs.)
// ---------------------------------------------------------------------------
template<typename OUT_T, bool BIAS, bool RELU>
__global__ __launch_bounds__(512, 2)
void gemm_bt3(const f16* __restrict__ A, const f16* __restrict__ Bm,
              OUT_T* __restrict__ C, const float* __restrict__ bias,
              int M, int N, int K, long sA, long sB, long sC)
{
    constexpr int TSA = 256 * 64;
    constexpr int TSB = 128 * 64;
    __shared__ alignas(16) f16 As[2 * TSA];
    __shared__ alignas(16) f16 Bs[2 * TSB];

    int bx = blockIdx.x, by = blockIdx.y;
    {   // XCD-locality remap (gy % 8 == 0 for all uses)
        const int gx = gridDim.x;
        const int l = by * gx + bx;
        const int W = gx * 8;
        const int ygrp = l / W;
        const int rem = l - ygrp * W;
        bx = rem >> 3;
        by = ygrp * 8 + (rem & 7);
    }
    const int z = blockIdx.z;
    A  += (long)z * sA;
    Bm += (long)z * sB;
    C  += (long)z * sC;

    const int tid  = threadIdx.x;
    const int wid  = tid >> 6;
    const int lane = tid & 63;
    const int lr = lane & 31;
    const int lh = lane >> 5;
    const int m0 = by * 256;
    const int n0 = bx * 128;
    const int wm = (wid >> 1) * 64;        // 4 M-waves: 0,64,128,192
    const int wn = (wid & 1) * 64;         // 2 N-waves: 0,64

    const int sr = tid >> 3;
    const int sg = ((tid & 7) ^ (sr & 7)) * 8;
    const f16* agS = A  + (long)(m0 + sr) * K + sg;
    const f16* bgS = Bm + (long)(n0 + sr) * K + sg;
    f16* aD = As + wid * (8 * 64);
    f16* bD = Bs + wid * (8 * 64);

    const int s7  = lr & 7;
    const int xs0 = ((0 + lh) ^ s7) * 8;
    const int xs1 = ((2 + lh) ^ s7) * 8;
    const int xs2 = ((4 + lh) ^ s7) * 8;
    const int xs3 = ((6 + lh) ^ s7) * 8;
    const f16* aR = As + (wm + lr) * 64;
    const f16* bR = Bs + (wn + lr) * 64;

    f32x16 acc[2][2];
#pragma unroll
    for (int mi = 0; mi < 2; ++mi)
#pragma unroll
        for (int ni = 0; ni < 2; ++ni)
#pragma unroll
            for (int r = 0; r < 16; ++r) acc[mi][ni][r] = 0.f;

    f16x8 b00, b01, b02, b03, b10, b11, b12, b13;

    const int NT = K >> 6;

#define GA3(buf, R0, kt) GLDS(agS + (long)(R0) * K + (kt), aD + (buf) * TSA + (R0) * 64)
#define GB3(buf, R0, kt) GLDS(bgS + (long)(R0) * K + (kt), bD + (buf) * TSB + (R0) * 64)

    // prologue: buf0 full (6 = oldest), buf1 B (2).  invariant: 2 outstanding.
    GB3(0,   0, 0);  GB3(0,  64, 0);
    GA3(0,   0, 0);  GA3(0,  64, 0);  GA3(0, 128, 0);  GA3(0, 192, 0);
    GB3(1,   0, 64); GB3(1,  64, 64);
    asm volatile("s_waitcnt vmcnt(2)" ::: "memory");   // buf0 fully landed
    __builtin_amdgcn_s_barrier();

#define MFMA8_3(mi) \
    acc[mi][0] = __builtin_amdgcn_mfma_f32_32x32x16_f16(af0, b00, acc[mi][0], 0, 0, 0); \
    acc[mi][1] = __builtin_amdgcn_mfma_f32_32x32x16_f16(af0, b10, acc[mi][1], 0, 0, 0); \
    acc[mi][0] = __builtin_amdgcn_mfma_f32_32x32x16_f16(af1, b01, acc[mi][0], 0, 0, 0); \
    acc[mi][1] = __builtin_amdgcn_mfma_f32_32x32x16_f16(af1, b11, acc[mi][1], 0, 0, 0); \
    acc[mi][0] = __builtin_amdgcn_mfma_f32_32x32x16_f16(af2, b02, acc[mi][0], 0, 0, 0); \
    acc[mi][1] = __builtin_amdgcn_mfma_f32_32x32x16_f16(af2, b12, acc[mi][1], 0, 0, 0); \
    acc[mi][0] = __builtin_amdgcn_mfma_f32_32x32x16_f16(af3, b03, acc[mi][0], 0, 0, 0); \
    acc[mi][1] = __builtin_amdgcn_mfma_f32_32x32x16_f16(af3, b13, acc[mi][1], 0, 0, 0);

#define PH3(buf, mi, VW, ...) { \
    f16x8 af0 = *(const f16x8*)(aR + (buf) * TSA + (mi) * 2048 + xs0); \
    f16x8 af1 = *(const f16x8*)(aR + (buf) * TSA + (mi) * 2048 + xs1); \
    f16x8 af2 = *(const f16x8*)(aR + (buf) * TSA + (mi) * 2048 + xs2); \
    f16x8 af3 = *(const f16x8*)(aR + (buf) * TSA + (mi) * 2048 + xs3); \
    if ((mi) == 0) { \
        b00 = *(const f16x8*)(bR + (buf) * TSB + xs0); \
        b01 = *(const f16x8*)(bR + (buf) * TSB + xs1); \
        b02 = *(const f16x8*)(bR + (buf) * TSB + xs2); \
        b03 = *(const f16x8*)(bR + (buf) * TSB + xs3); \
        b10 = *(const f16x8*)(bR + (buf) * TSB + 2048 + xs0); \
        b11 = *(const f16x8*)(bR + (buf) * TSB + 2048 + xs1); \
        b12 = *(const f16x8*)(bR + (buf) * TSB + 2048 + xs2); \
        b13 = *(const f16x8*)(bR + (buf) * TSB + 2048 + xs3); \
    } \
    __VA_ARGS__ \
    __builtin_amdgcn_s_barrier(); \
    __builtin_amdgcn_s_setprio(1); \
    MFMA8_3(mi) \
    __builtin_amdgcn_s_setprio(0); \
    if (VW) { asm volatile("s_waitcnt vmcnt(2)" ::: "memory"); } \
    __builtin_amdgcn_s_barrier(); \
}

    for (int i = 0; i < NT / 2; ++i) {
        const long k1 = (long)(2 * i + 1) << 6;                           // tile t+1
        const long kA = (2 * i + 2 < NT) ? ((long)(2 * i + 2) << 6) : 0;  // tile t+2
        const long kB = (2 * i + 3 < NT) ? ((long)(2 * i + 3) << 6) : 0;  // tile t+3
        PH3(0, 0, 0, GA3(1,   0, k1); GA3(1,  64, k1); GA3(1, 128, k1); GA3(1, 192, k1);)
        PH3(0, 1, 1, GB3(0,   0, kA); GB3(0,  64, kA);)
        PH3(1, 0, 0, GA3(0,   0, kA); GA3(0,  64, kA); GA3(0, 128, kA); GA3(0, 192, kA);)
        PH3(1, 1, 1, GB3(1,   0, kB); GB3(1,  64, kB);)
    }

    asm volatile("s_waitcnt vmcnt(0)" ::: "memory");

    // C/D layout (32x32): col = lane&31, row = (reg&3) + 8*(reg>>2) + 4*(lane>>5)
#pragma unroll
    for (int ni = 0; ni < 2; ++ni) {
        const int gc = n0 + wn + ni * 32 + lr;
        const float bv = BIAS ? bias[gc] : 0.0f;
#pragma unroll
        for (int mi = 0; mi < 2; ++mi) {
#pragma unroll
            for (int r = 0; r < 16; ++r) {
                const int row = (r & 3) + 8 * (r >> 2) + 4 * lh;
                const int gr = m0 + wm + mi * 32 + row;
                float v = acc[mi][ni][r] + bv;
                if (RELU) v = fmaxf(v, 0.0f);
                C[(long)gr * N + gc] = (OUT_T)v;
            }
        }
    }
#undef PH3
#undef MFMA8_3
#undef GA3
#undef GB3
}

// ---------------------------------------------------------------------------
__global__ __launch_bounds__(256)
void cast_f32_f16(const float* __restrict__ X, f16* __restrict__ Y)
{
    const long i = ((long)blockIdx.x * 256 + threadIdx.x) * 8;
    float4 a = *(const float4*)(X + i);
    float4 b = *(const float4*)(X + i + 4);
    f16x8 h = {(f16)a.x, (f16)a.y, (f16)a.z, (f16)a.w,
               (f16)b.x, (f16)b.y, (f16)b.z, (f16)b.w};
    *(f16x8*)(Y + i) = h;
}

// proj_q fp32 [2048 x 1024] per batch -> qB fp16 (row-major) AND qBt fp16 [1024 x 2048]
__global__ __launch_bounds__(256)
void cast_q_dual(const float* __restrict__ X, f16* __restrict__ Yrow,
                 f16* __restrict__ Ytr)
{
    __shared__ f16 t[64][72];
    const float* Xb = X + (long)blockIdx.z * (2048L * 1024);
    f16* Yrb = Yrow + (long)blockIdx.z * (2048L * 1024);
    f16* Ytb = Ytr  + (long)blockIdx.z * (1024L * 2048);
    const int r0 = blockIdx.y * 64;
    const int c0 = blockIdx.x * 64;
    const int tid = threadIdx.x;
    const int tr = tid >> 4;
    const int tc = (tid & 15) * 4;
#pragma unroll
    for (int rr = 0; rr < 64; rr += 16) {
        float4 v = *(const float4*)(Xb + (long)(r0 + tr + rr) * 1024 + c0 + tc);
        f16x4 h = {(f16)v.x, (f16)v.y, (f16)v.z, (f16)v.w};
        *(f16x4*)&t[tr + rr][tc] = h;
        *(f16x4*)(Yrb + (long)(r0 + tr + rr) * 1024 + c0 + tc) = h;
    }
    __syncthreads();
#pragma unroll
    for (int rr = 0; rr < 64; rr += 16) {
        const int orow = tr + rr;
        f16x4 o = {t[tc + 0][orow], t[tc + 1][orow], t[tc + 2][orow], t[tc + 3][orow]};
        *(f16x4*)(Ytb + (long)(c0 + orow) * 2048 + r0 + tc) = o;
    }
}

// rowwise softmax over 2048 fp32 -> fp16
__global__ __launch_bounds__(256)
void softmax_p(const float* __restrict__ S, f16* __restrict__ P)
{
    const long row = blockIdx.x;
    const float* s = S + row * 2048;
    f16* p = P + row * 2048;
    const int tid = threadIdx.x;
    const int wid = tid >> 6, lane = tid & 63;

    float4 a = *(const float4*)(s + tid * 8);
    float4 b = *(const float4*)(s + tid * 8 + 4);
    float v[8] = {a.x, a.y, a.z, a.w, b.x, b.y, b.z, b.w};

    float m = v[0];
#pragma unroll
    for (int j = 1; j < 8; ++j) m = fmaxf(m, v[j]);
#pragma unroll
    for (int off = 32; off > 0; off >>= 1) m = fmaxf(m, __shfl_xor(m, off, 64));

    __shared__ float red[8];
    if (lane == 0) red[wid] = m;
    __syncthreads();
    m = fmaxf(fmaxf(red[0], red[1]), fmaxf(red[2], red[3]));

    float sum = 0.f;
#pragma unroll
    for (int j = 0; j < 8; ++j) { v[j] = __expf(v[j] - m); sum += v[j]; }
#pragma unroll
    for (int off = 32; off > 0; off >>= 1) sum += __shfl_xor(sum, off, 64);
    if (lane == 0) red[4 + wid] = sum;
    __syncthreads();
    sum = red[4] + red[5] + red[6] + red[7];

    const float inv = 1.0f / sum;
    f16x8 h = {(f16)(v[0] * inv), (f16)(v[1] * inv), (f16)(v[2] * inv), (f16)(v[3] * inv),
               (f16)(v[4] * inv), (f16)(v[5] * inv), (f16)(v[6] * inv), (f16)(v[7] * inv)};
    *(f16x8*)(p + tid * 8) = h;
}

// ---------------------------------------------------------------------------
extern "C" void kernel_launch(void* const* d_in, const int* in_sizes, int n_in,
                              void* d_out, int out_size, void* d_ws, size_t ws_size,
                              hipStream_t stream)
{
    const float* proj_p = (const float*)d_in[0];  // [16,2048,1024]
    const float* proj_q = (const float*)d_in[1];  // [16,2048,1024]
    const float* W      = (const float*)d_in[2];  // [1024,1024]
    const float* bias   = (const float*)d_in[3];  // [1024]
    float* out = (float*)d_out;

    constexpr long Bc = 16, L = 2048, H = 1024, NB = 4;
    constexpr long nPQ = Bc * L * H;              // 33,554,432 elements

    char* ws = (char*)d_ws;
    f16*   pB  = (f16*)(ws + 0L);                 // 67,108,864 B
    f16*   qB  = (f16*)(ws + 67108864L);          // 67,108,864 B
    f16*   qBt = (f16*)(ws + 134217728L);         // 67,108,864 B  [B][H][L]
    f16*   tQ  = (f16*)(ws + 201326592L);         // 67,108,864 B
    f16*   aV  = (f16*)(ws + 268435456L);         // 67,108,864 B
    f16*   Wb  = (f16*)(ws + 335544320L);         //  2,097,152 B
    float* S   = (float*)(ws + 337641472L);       // 67,108,864 B (4 batches fp32)
    f16*   P   = (f16*)(ws + 404750336L);         // 33,554,432 B (4 batches fp16)

    cast_f32_f16<<<nPQ / (256 * 8), 256, 0, stream>>>(proj_p, pB);
    cast_f32_f16<<<(H * H) / (256 * 8), 256, 0, stream>>>(W, Wb);
    cast_q_dual<<<dim3(16, 32, 16), 256, 0, stream>>>(proj_q, qB, qBt);

    // G1: tQ[b,q,o] = qB[b,q,:] . Wb[o,:] + bias[o]   (256-tile, 4-wave)
    gemm_bt2<f16, true, false><<<dim3(H / 256, (Bc * L) / 256, 1), 256, 0, stream>>>(
        qB, Wb, tQ, bias, (int)(Bc * L), (int)H, (int)H, 0, 0, 0);

    for (int c = 0; c < 4; ++c) {
        const long boff = (long)c * NB * L * H;
        // G2: S[p,q] = pB[p,:] . tQ[q,:]   (fp32 out, 256-tile, 4-wave)
        gemm_bt2<float, false, false><<<dim3(L / 256, L / 256, NB), 256, 0, stream>>>(
            pB + boff, tQ + boff, S, nullptr, (int)L, (int)L, (int)H,
            L * H, L * H, L * L);
        // softmax rows -> P fp16
        softmax_p<<<NB * L, 256, 0, stream>>>(S, P);
        // G3: aV[p,h] = P[p,:] . qBt[h,:]   (256x128-tile 4-phase, K=2048)
        gemm_bt3<f16, false, false><<<dim3(H / 128, L / 256, NB), 512, 0, stream>>>(
            P, qBt + (long)c * NB * H * L, aV + boff, nullptr, (int)L, (int)H, (int)L,
            L * L, H * L, L * H);
    }

    // G4: out = relu(aV . Wb^T + bias)  (fp32 out, 256-tile, 4-wave)
    gemm_bt2<float, false, true><<<dim3(H / 256, (Bc * L) / 256, 1), 256, 0, stream>>>(
        aV, Wb, out, bias, (int)(Bc * L), (int)H, (int)H, 0, 0, 0);
}

// Round 7
// 928.196 us; speedup vs baseline: 1.0391x; 1.0391x over previous
//
#include <hip/hip_runtime.h>

typedef _Float16 f16;
typedef _Float16 f16x8 __attribute__((ext_vector_type(8)));
typedef _Float16 f16x4 __attribute__((ext_vector_type(4)));
typedef float    f32x16 __attribute__((ext_vector_type(16)));

#define GLDS(gp, lp) __builtin_amdgcn_global_load_lds( \
    (const __attribute__((address_space(1))) void*)(gp), \
    (__attribute__((address_space(3))) void*)(lp), 16, 0, 0)

// ---------------------------------------------------------------------------
// 256x256 tile, BK=64, 512 threads (8 waves 2x4, 128x64 per wave), 8-phase
// K-loop with counted vmcnt(6) prefetch, LDS XOR-swizzle, s_setprio around
// MFMA clusters.  Double-buffered 128 KiB LDS.  (Proven R5 form: B via LDS —
// B-direct-from-global regressed 1.5x (L2 row-scatter); 4-wave/128x128
// regressed 6% (1 wave/SIMD kills MFMA||ds_read cross-wave overlap).
// No explicit lgkmcnt(0): compiler emits progressive lgkmcnt per frag dep.)
// ---------------------------------------------------------------------------
template<typename OUT_T, bool BIAS, bool RELU>
__global__ __launch_bounds__(512, 2)
void gemm_bt2(const f16* __restrict__ A, const f16* __restrict__ Bm,
              OUT_T* __restrict__ C, const float* __restrict__ bias,
              int M, int N, int K, long sA, long sB, long sC)
{
    constexpr int TSZ = 256 * 64;          // f16 elements per tile buffer
    __shared__ alignas(16) f16 As[2 * TSZ];
    __shared__ alignas(16) f16 Bs[2 * TSZ];

    int bx = blockIdx.x, by = blockIdx.y;
    {   // XCD-locality remap (gy % 8 == 0 for all uses)
        const int gx = gridDim.x;
        const int l = by * gx + bx;
        const int W = gx * 8;
        const int ygrp = l / W;
        const int rem = l - ygrp * W;
        bx = rem >> 3;
        by = ygrp * 8 + (rem & 7);
    }
    const int z = blockIdx.z;
    A  += (long)z * sA;
    Bm += (long)z * sB;
    C  += (long)z * sC;

    const int tid  = threadIdx.x;
    const int wid  = tid >> 6;
    const int lane = tid & 63;
    const int lr = lane & 31;
    const int lh = lane >> 5;
    const int m0 = by * 256;
    const int n0 = bx * 256;
    const int wm = (wid >> 2) * 128;       // wave row: 0 or 128
    const int wn = (wid & 3) * 64;         // wave col: 0,64,128,192

    // staging: one GLDS call covers 64 rows (8 rows/wave, 8 x 16B slots/row).
    // LDS row r slot s holds source k-segment (s ^ (r&7))  [XOR swizzle]
    const int sr = tid >> 3;                         // row within 64-row call
    const int sg = ((tid & 7) ^ (sr & 7)) * 8;       // pre-swizzled source col
    const f16* agS = A  + (long)(m0 + sr) * K + sg;
    const f16* bgS = Bm + (long)(n0 + sr) * K + sg;
    f16* aD = As + wid * (8 * 64);                   // wave-uniform LDS base
    f16* bD = Bs + wid * (8 * 64);

    // fragment read: k-segment g = 2*ks + lh at slot g ^ (row&7)
    const int s7  = lr & 7;
    const int xs0 = ((0 + lh) ^ s7) * 8;
    const int xs1 = ((2 + lh) ^ s7) * 8;
    const int xs2 = ((4 + lh) ^ s7) * 8;
    const int xs3 = ((6 + lh) ^ s7) * 8;
    const f16* aR = As + (wm + lr) * 64;
    const f16* bR = Bs + (wn + lr) * 64;

    f32x16 acc[4][2];
#pragma unroll
    for (int mi = 0; mi < 4; ++mi)
#pragma unroll
        for (int ni = 0; ni < 2; ++ni)
#pragma unroll
            for (int r = 0; r < 16; ++r) acc[mi][ni][r] = 0.f;

    f16x8 b00, b01, b02, b03, b10, b11, b12, b13;

    const int NT = K >> 6;

#define GAc(buf, R0, kt) GLDS(agS + (long)(R0) * K + (kt), aD + (buf) * TSZ + (R0) * 64)
#define GBc(buf, R0, kt) GLDS(bgS + (long)(R0) * K + (kt), bD + (buf) * TSZ + (R0) * 64)

    // prologue: tile0 -> buf0 (B then A = oldest 8), tile1 -> buf1 (B all, A head)
    GBc(0,   0, 0);  GBc(0,  64, 0);  GBc(0, 128, 0);  GBc(0, 192, 0);
    GAc(0,   0, 0);  GAc(0,  64, 0);  GAc(0, 128, 0);  GAc(0, 192, 0);
    GBc(1,   0, 64); GBc(1,  64, 64); GBc(1, 128, 64); GBc(1, 192, 64);
    GAc(1,   0, 64); GAc(1, 128, 64);
    asm volatile("s_waitcnt vmcnt(6)" ::: "memory");   // buf0 fully landed
    __builtin_amdgcn_s_barrier();

#define MFMA8(mi) \
    acc[mi][0] = __builtin_amdgcn_mfma_f32_32x32x16_f16(af0, b00, acc[mi][0], 0, 0, 0); \
    acc[mi][1] = __builtin_amdgcn_mfma_f32_32x32x16_f16(af0, b10, acc[mi][1], 0, 0, 0); \
    acc[mi][0] = __builtin_amdgcn_mfma_f32_32x32x16_f16(af1, b01, acc[mi][0], 0, 0, 0); \
    acc[mi][1] = __builtin_amdgcn_mfma_f32_32x32x16_f16(af1, b11, acc[mi][1], 0, 0, 0); \
    acc[mi][0] = __builtin_amdgcn_mfma_f32_32x32x16_f16(af2, b02, acc[mi][0], 0, 0, 0); \
    acc[mi][1] = __builtin_amdgcn_mfma_f32_32x32x16_f16(af2, b12, acc[mi][1], 0, 0, 0); \
    acc[mi][0] = __builtin_amdgcn_mfma_f32_32x32x16_f16(af3, b03, acc[mi][0], 0, 0, 0); \
    acc[mi][1] = __builtin_amdgcn_mfma_f32_32x32x16_f16(af3, b13, acc[mi][1], 0, 0, 0);

// Phase: frag ds_reads | GLDS issues | barrier | 8 MFMA (compiler inserts
// progressive lgkmcnt per frag dependency) | [vmcnt gate] | barrier
#define PH(buf, mi, VW, ...) { \
    f16x8 af0 = *(const f16x8*)(aR + (buf) * TSZ + (mi) * 2048 + xs0); \
    f16x8 af1 = *(const f16x8*)(aR + (buf) * TSZ + (mi) * 2048 + xs1); \
    f16x8 af2 = *(const f16x8*)(aR + (buf) * TSZ + (mi) * 2048 + xs2); \
    f16x8 af3 = *(const f16x8*)(aR + (buf) * TSZ + (mi) * 2048 + xs3); \
    if ((mi) == 0) { \
        b00 = *(const f16x8*)(bR + (buf) * TSZ + xs0); \
        b01 = *(const f16x8*)(bR + (buf) * TSZ + xs1); \
        b02 = *(const f16x8*)(bR + (buf) * TSZ + xs2); \
        b03 = *(const f16x8*)(bR + (buf) * TSZ + xs3); \
        b10 = *(const f16x8*)(bR + (buf) * TSZ + 2048 + xs0); \
        b11 = *(const f16x8*)(bR + (buf) * TSZ + 2048 + xs1); \
        b12 = *(const f16x8*)(bR + (buf) * TSZ + 2048 + xs2); \
        b13 = *(const f16x8*)(bR + (buf) * TSZ + 2048 + xs3); \
    } \
    __VA_ARGS__ \
    __builtin_amdgcn_s_barrier(); \
    __builtin_amdgcn_s_setprio(1); \
    MFMA8(mi) \
    __builtin_amdgcn_s_setprio(0); \
    if (VW) { asm volatile("s_waitcnt vmcnt(6)" ::: "memory"); } \
    __builtin_amdgcn_s_barrier(); \
}

    for (int i = 0; i < NT / 2; ++i) {
        const long k1 = (long)(2 * i + 1) << 6;                           // tile t+1 (tail)
        const long kA = (2 * i + 2 < NT) ? ((long)(2 * i + 2) << 6) : 0;  // tile t+2
        const long kB = (2 * i + 3 < NT) ? ((long)(2 * i + 3) << 6) : 0;  // tile t+3
        PH(0, 0, 0, GAc(1,  64, k1); GAc(1, 192, k1);)
        PH(0, 1, 0, GBc(0,   0, kA); GBc(0,  64, kA);)
        PH(0, 2, 0, GBc(0, 128, kA); GBc(0, 192, kA);)
        PH(0, 3, 1, GAc(0,   0, kA); GAc(0, 128, kA);)
        PH(1, 0, 0, GAc(0,  64, kA); GAc(0, 192, kA);)
        PH(1, 1, 0, GBc(1,   0, kB); GBc(1,  64, kB);)
        PH(1, 2, 0, GBc(1, 128, kB); GBc(1, 192, kB);)
        PH(1, 3, 1, GAc(1,   0, kB); GAc(1, 128, kB);)
    }

    asm volatile("s_waitcnt vmcnt(0)" ::: "memory");    // drain before LDS dealloc

    // C/D layout (32x32): col = lane&31, row = (reg&3) + 8*(reg>>2) + 4*(lane>>5)
#pragma unroll
    for (int ni = 0; ni < 2; ++ni) {
        const int gc = n0 + wn + ni * 32 + lr;
        const float bv = BIAS ? bias[gc] : 0.0f;
#pragma unroll
        for (int mi = 0; mi < 4; ++mi) {
#pragma unroll
            for (int r = 0; r < 16; ++r) {
                const int row = (r & 3) + 8 * (r >> 2) + 4 * lh;
                const int gr = m0 + wm + mi * 32 + row;
                float v = acc[mi][ni][r] + bv;
                if (RELU) v = fmaxf(v, 0.0f);
                C[(long)gr * N + gc] = (OUT_T)v;
            }
        }
    }
#undef PH
#undef MFMA8
#undef GAc
#undef GBc
}

// ---------------------------------------------------------------------------
// 256x128 tile, BK=64, 512 threads (8 waves 4M x 2N, 64x64 per wave),
// 4-phase K-loop, B through LDS.  LDS 96 KiB, XOR-swizzled.  (Proven R5 form,
// unchanged — used for G3 where a 256x256 grid would underfill CUs.)
// ---------------------------------------------------------------------------
template<typename OUT_T, bool BIAS, bool RELU>
__global__ __launch_bounds__(512, 2)
void gemm_bt3(const f16* __restrict__ A, const f16* __restrict__ Bm,
              OUT_T* __restrict__ C, const float* __restrict__ bias,
              int M, int N, int K, long sA, long sB, long sC)
{
    constexpr int TSA = 256 * 64;
    constexpr int TSB = 128 * 64;
    __shared__ alignas(16) f16 As[2 * TSA];
    __shared__ alignas(16) f16 Bs[2 * TSB];

    int bx = blockIdx.x, by = blockIdx.y;
    {   // XCD-locality remap (gy % 8 == 0 for all uses)
        const int gx = gridDim.x;
        const int l = by * gx + bx;
        const int W = gx * 8;
        const int ygrp = l / W;
        const int rem = l - ygrp * W;
        bx = rem >> 3;
        by = ygrp * 8 + (rem & 7);
    }
    const int z = blockIdx.z;
    A  += (long)z * sA;
    Bm += (long)z * sB;
    C  += (long)z * sC;

    const int tid  = threadIdx.x;
    const int wid  = tid >> 6;
    const int lane = tid & 63;
    const int lr = lane & 31;
    const int lh = lane >> 5;
    const int m0 = by * 256;
    const int n0 = bx * 128;
    const int wm = (wid >> 1) * 64;        // 4 M-waves: 0,64,128,192
    const int wn = (wid & 1) * 64;         // 2 N-waves: 0,64

    const int sr = tid >> 3;
    const int sg = ((tid & 7) ^ (sr & 7)) * 8;
    const f16* agS = A  + (long)(m0 + sr) * K + sg;
    const f16* bgS = Bm + (long)(n0 + sr) * K + sg;
    f16* aD = As + wid * (8 * 64);
    f16* bD = Bs + wid * (8 * 64);

    const int s7  = lr & 7;
    const int xs0 = ((0 + lh) ^ s7) * 8;
    const int xs1 = ((2 + lh) ^ s7) * 8;
    const int xs2 = ((4 + lh) ^ s7) * 8;
    const int xs3 = ((6 + lh) ^ s7) * 8;
    const f16* aR = As + (wm + lr) * 64;
    const f16* bR = Bs + (wn + lr) * 64;

    f32x16 acc[2][2];
#pragma unroll
    for (int mi = 0; mi < 2; ++mi)
#pragma unroll
        for (int ni = 0; ni < 2; ++ni)
#pragma unroll
            for (int r = 0; r < 16; ++r) acc[mi][ni][r] = 0.f;

    f16x8 b00, b01, b02, b03, b10, b11, b12, b13;

    const int NT = K >> 6;

#define GA3(buf, R0, kt) GLDS(agS + (long)(R0) * K + (kt), aD + (buf) * TSA + (R0) * 64)
#define GB3(buf, R0, kt) GLDS(bgS + (long)(R0) * K + (kt), bD + (buf) * TSB + (R0) * 64)

    // prologue: buf0 full (6 = oldest), buf1 B (2).  invariant: 2 outstanding.
    GB3(0,   0, 0);  GB3(0,  64, 0);
    GA3(0,   0, 0);  GA3(0,  64, 0);  GA3(0, 128, 0);  GA3(0, 192, 0);
    GB3(1,   0, 64); GB3(1,  64, 64);
    asm volatile("s_waitcnt vmcnt(2)" ::: "memory");   // buf0 fully landed
    __builtin_amdgcn_s_barrier();

#define MFMA8_3(mi) \
    acc[mi][0] = __builtin_amdgcn_mfma_f32_32x32x16_f16(af0, b00, acc[mi][0], 0, 0, 0); \
    acc[mi][1] = __builtin_amdgcn_mfma_f32_32x32x16_f16(af0, b10, acc[mi][1], 0, 0, 0); \
    acc[mi][0] = __builtin_amdgcn_mfma_f32_32x32x16_f16(af1, b01, acc[mi][0], 0, 0, 0); \
    acc[mi][1] = __builtin_amdgcn_mfma_f32_32x32x16_f16(af1, b11, acc[mi][1], 0, 0, 0); \
    acc[mi][0] = __builtin_amdgcn_mfma_f32_32x32x16_f16(af2, b02, acc[mi][0], 0, 0, 0); \
    acc[mi][1] = __builtin_amdgcn_mfma_f32_32x32x16_f16(af2, b12, acc[mi][1], 0, 0, 0); \
    acc[mi][0] = __builtin_amdgcn_mfma_f32_32x32x16_f16(af3, b03, acc[mi][0], 0, 0, 0); \
    acc[mi][1] = __builtin_amdgcn_mfma_f32_32x32x16_f16(af3, b13, acc[mi][1], 0, 0, 0);

#define PH3(buf, mi, VW, ...) { \
    f16x8 af0 = *(const f16x8*)(aR + (buf) * TSA + (mi) * 2048 + xs0); \
    f16x8 af1 = *(const f16x8*)(aR + (buf) * TSA + (mi) * 2048 + xs1); \
    f16x8 af2 = *(const f16x8*)(aR + (buf) * TSA + (mi) * 2048 + xs2); \
    f16x8 af3 = *(const f16x8*)(aR + (buf) * TSA + (mi) * 2048 + xs3); \
    if ((mi) == 0) { \
        b00 = *(const f16x8*)(bR + (buf) * TSB + xs0); \
        b01 = *(const f16x8*)(bR + (buf) * TSB + xs1); \
        b02 = *(const f16x8*)(bR + (buf) * TSB + xs2); \
        b03 = *(const f16x8*)(bR + (buf) * TSB + xs3); \
        b10 = *(const f16x8*)(bR + (buf) * TSB + 2048 + xs0); \
        b11 = *(const f16x8*)(bR + (buf) * TSB + 2048 + xs1); \
        b12 = *(const f16x8*)(bR + (buf) * TSB + 2048 + xs2); \
        b13 = *(const f16x8*)(bR + (buf) * TSB + 2048 + xs3); \
    } \
    __VA_ARGS__ \
    __builtin_amdgcn_s_barrier(); \
    __builtin_amdgcn_s_setprio(1); \
    MFMA8_3(mi) \
    __builtin_amdgcn_s_setprio(0); \
    if (VW) { asm volatile("s_waitcnt vmcnt(2)" ::: "memory"); } \
    __builtin_amdgcn_s_barrier(); \
}

    for (int i = 0; i < NT / 2; ++i) {
        const long k1 = (long)(2 * i + 1) << 6;                           // tile t+1
        const long kA = (2 * i + 2 < NT) ? ((long)(2 * i + 2) << 6) : 0;  // tile t+2
        const long kB = (2 * i + 3 < NT) ? ((long)(2 * i + 3) << 6) : 0;  // tile t+3
        PH3(0, 0, 0, GA3(1,   0, k1); GA3(1,  64, k1); GA3(1, 128, k1); GA3(1, 192, k1);)
        PH3(0, 1, 1, GB3(0,   0, kA); GB3(0,  64, kA);)
        PH3(1, 0, 0, GA3(0,   0, kA); GA3(0,  64, kA); GA3(0, 128, kA); GA3(0, 192, kA);)
        PH3(1, 1, 1, GB3(1,   0, kB); GB3(1,  64, kB);)
    }

    asm volatile("s_waitcnt vmcnt(0)" ::: "memory");

    // C/D layout (32x32): col = lane&31, row = (reg&3) + 8*(reg>>2) + 4*(lane>>5)
#pragma unroll
    for (int ni = 0; ni < 2; ++ni) {
        const int gc = n0 + wn + ni * 32 + lr;
        const float bv = BIAS ? bias[gc] : 0.0f;
#pragma unroll
        for (int mi = 0; mi < 2; ++mi) {
#pragma unroll
            for (int r = 0; r < 16; ++r) {
                const int row = (r & 3) + 8 * (r >> 2) + 4 * lh;
                const int gr = m0 + wm + mi * 32 + row;
                float v = acc[mi][ni][r] + bv;
                if (RELU) v = fmaxf(v, 0.0f);
                C[(long)gr * N + gc] = (OUT_T)v;
            }
        }
    }
#undef PH3
#undef MFMA8_3
#undef GA3
#undef GB3
}

// ---------------------------------------------------------------------------
__global__ __launch_bounds__(256)
void cast_f32_f16(const float* __restrict__ X, f16* __restrict__ Y)
{
    const long i = ((long)blockIdx.x * 256 + threadIdx.x) * 8;
    float4 a = *(const float4*)(X + i);
    float4 b = *(const float4*)(X + i + 4);
    f16x8 h = {(f16)a.x, (f16)a.y, (f16)a.z, (f16)a.w,
               (f16)b.x, (f16)b.y, (f16)b.z, (f16)b.w};
    *(f16x8*)(Y + i) = h;
}

// proj_q fp32 [2048 x 1024] per batch -> qB fp16 (row-major) AND qBt fp16 [1024 x 2048]
__global__ __launch_bounds__(256)
void cast_q_dual(const float* __restrict__ X, f16* __restrict__ Yrow,
                 f16* __restrict__ Ytr)
{
    __shared__ f16 t[64][72];
    const float* Xb = X + (long)blockIdx.z * (2048L * 1024);
    f16* Yrb = Yrow + (long)blockIdx.z * (2048L * 1024);
    f16* Ytb = Ytr  + (long)blockIdx.z * (1024L * 2048);
    const int r0 = blockIdx.y * 64;
    const int c0 = blockIdx.x * 64;
    const int tid = threadIdx.x;
    const int tr = tid >> 4;
    const int tc = (tid & 15) * 4;
#pragma unroll
    for (int rr = 0; rr < 64; rr += 16) {
        float4 v = *(const float4*)(Xb + (long)(r0 + tr + rr) * 1024 + c0 + tc);
        f16x4 h = {(f16)v.x, (f16)v.y, (f16)v.z, (f16)v.w};
        *(f16x4*)&t[tr + rr][tc] = h;
        *(f16x4*)(Yrb + (long)(r0 + tr + rr) * 1024 + c0 + tc) = h;
    }
    __syncthreads();
#pragma unroll
    for (int rr = 0; rr < 64; rr += 16) {
        const int orow = tr + rr;
        f16x4 o = {t[tc + 0][orow], t[tc + 1][orow], t[tc + 2][orow], t[tc + 3][orow]};
        *(f16x4*)(Ytb + (long)(c0 + orow) * 2048 + r0 + tc) = o;
    }
}

// rowwise softmax over 2048 **f16** scores -> fp16 probabilities
// (S stored f16: softmax is near-one-hot at sigma_S~32, and S already carries
//  ~0.03-0.1 abs error from the f16 input casts; f16 storage adds <= ulp/2
//  ~0.03 which is invisible after exp-normalization.)
__global__ __launch_bounds__(256)
void softmax_ph(const f16* __restrict__ S, f16* __restrict__ P)
{
    const long row = blockIdx.x;
    const f16* s = S + row * 2048;
    f16* p = P + row * 2048;
    const int tid = threadIdx.x;
    const int wid = tid >> 6, lane = tid & 63;

    f16x8 hv = *(const f16x8*)(s + tid * 8);
    float v[8] = {(float)hv[0], (float)hv[1], (float)hv[2], (float)hv[3],
                  (float)hv[4], (float)hv[5], (float)hv[6], (float)hv[7]};

    float m = v[0];
#pragma unroll
    for (int j = 1; j < 8; ++j) m = fmaxf(m, v[j]);
#pragma unroll
    for (int off = 32; off > 0; off >>= 1) m = fmaxf(m, __shfl_xor(m, off, 64));

    __shared__ float red[8];
    if (lane == 0) red[wid] = m;
    __syncthreads();
    m = fmaxf(fmaxf(red[0], red[1]), fmaxf(red[2], red[3]));

    float sum = 0.f;
#pragma unroll
    for (int j = 0; j < 8; ++j) { v[j] = __expf(v[j] - m); sum += v[j]; }
#pragma unroll
    for (int off = 32; off > 0; off >>= 1) sum += __shfl_xor(sum, off, 64);
    if (lane == 0) red[4 + wid] = sum;
    __syncthreads();
    sum = red[4] + red[5] + red[6] + red[7];

    const float inv = 1.0f / sum;
    f16x8 h = {(f16)(v[0] * inv), (f16)(v[1] * inv), (f16)(v[2] * inv), (f16)(v[3] * inv),
               (f16)(v[4] * inv), (f16)(v[5] * inv), (f16)(v[6] * inv), (f16)(v[7] * inv)};
    *(f16x8*)(p + tid * 8) = h;
}

// ---------------------------------------------------------------------------
extern "C" void kernel_launch(void* const* d_in, const int* in_sizes, int n_in,
                              void* d_out, int out_size, void* d_ws, size_t ws_size,
                              hipStream_t stream)
{
    const float* proj_p = (const float*)d_in[0];  // [16,2048,1024]
    const float* proj_q = (const float*)d_in[1];  // [16,2048,1024]
    const float* W      = (const float*)d_in[2];  // [1024,1024]
    const float* bias   = (const float*)d_in[3];  // [1024]
    float* out = (float*)d_out;

    constexpr long Bc = 16, L = 2048, H = 1024, NB = 4;
    constexpr long nPQ = Bc * L * H;              // 33,554,432 elements

    char* ws = (char*)d_ws;
    f16*   pB  = (f16*)(ws + 0L);                 // 67,108,864 B
    f16*   qB  = (f16*)(ws + 67108864L);          // 67,108,864 B
    f16*   qBt = (f16*)(ws + 134217728L);         // 67,108,864 B  [B][H][L]
    f16*   tQ  = (f16*)(ws + 201326592L);         // 67,108,864 B
    f16*   aV  = (f16*)(ws + 268435456L);         // 67,108,864 B
    f16*   Wb  = (f16*)(ws + 335544320L);         //  2,097,152 B
    f16*   Sh  = (f16*)(ws + 337641472L);         // 33,554,432 B (4 batches f16)
    f16*   P   = (f16*)(ws + 404750336L);         // 33,554,432 B (4 batches fp16)

    cast_f32_f16<<<nPQ / (256 * 8), 256, 0, stream>>>(proj_p, pB);
    cast_f32_f16<<<(H * H) / (256 * 8), 256, 0, stream>>>(W, Wb);
    cast_q_dual<<<dim3(16, 32, 16), 256, 0, stream>>>(proj_q, qB, qBt);

    // G1: tQ[b,q,o] = qB[b,q,:] . Wb[o,:] + bias[o]   (256-tile 8-phase)
    gemm_bt2<f16, true, false><<<dim3(H / 256, (Bc * L) / 256, 1), 512, 0, stream>>>(
        qB, Wb, tQ, bias, (int)(Bc * L), (int)H, (int)H, 0, 0, 0);

    for (int c = 0; c < 4; ++c) {
        const long boff = (long)c * NB * L * H;
        // G2: S[p,q] = pB[p,:] . tQ[q,:]   (f16 out, 256-tile 8-phase)
        gemm_bt2<f16, false, false><<<dim3(L / 256, L / 256, NB), 512, 0, stream>>>(
            pB + boff, tQ + boff, Sh, nullptr, (int)L, (int)L, (int)H,
            L * H, L * H, L * L);
        // softmax rows (f16 in) -> P fp16
        softmax_ph<<<NB * L, 256, 0, stream>>>(Sh, P);
        // G3: aV[p,h] = P[p,:] . qBt[h,:]   (256x128-tile 4-phase, K=2048)
        gemm_bt3<f16, false, false><<<dim3(H / 128, L / 256, NB), 512, 0, stream>>>(
            P, qBt + (long)c * NB * H * L, aV + boff, nullptr, (int)L, (int)H, (int)L,
            L * L, H * L, L * H);
    }

    // G4: out = relu(aV . Wb^T + bias)  (fp32 out, 256-tile 8-phase)
    gemm_bt2<float, false, true><<<dim3(H / 256, (Bc * L) / 256, 1), 512, 0, stream>>>(
        aV, Wb, out, bias, (int)(Bc * L), (int)H, (int)H, 0, 0, 0);
}

// Round 8
// 848.650 us; speedup vs baseline: 1.1365x; 1.0937x over previous
//
#include <hip/hip_runtime.h>

typedef _Float16 f16;
typedef _Float16 f16x8 __attribute__((ext_vector_type(8)));
typedef _Float16 f16x4 __attribute__((ext_vector_type(4)));
typedef float    f32x16 __attribute__((ext_vector_type(16)));

#define GLDS(gp, lp) __builtin_amdgcn_global_load_lds( \
    (const __attribute__((address_space(1))) void*)(gp), \
    (__attribute__((address_space(3))) void*)(lp), 16, 0, 0)

// ---------------------------------------------------------------------------
// 256x256 tile, BK=64, 512 threads (8 waves 2x4, 128x64 per wave), 8-phase
// K-loop with counted vmcnt(6) prefetch, LDS XOR-swizzle, s_setprio around
// MFMA clusters.  Double-buffered 128 KiB LDS.  (Proven R5/R7 form.)
// ---------------------------------------------------------------------------
template<typename OUT_T, bool BIAS, bool RELU>
__global__ __launch_bounds__(512, 2)
void gemm_bt2(const f16* __restrict__ A, const f16* __restrict__ Bm,
              OUT_T* __restrict__ C, const float* __restrict__ bias,
              int M, int N, int K, long sA, long sB, long sC)
{
    constexpr int TSZ = 256 * 64;          // f16 elements per tile buffer
    __shared__ alignas(16) f16 As[2 * TSZ];
    __shared__ alignas(16) f16 Bs[2 * TSZ];

    int bx = blockIdx.x, by = blockIdx.y;
    {   // XCD-locality remap (gy % 8 == 0 for all uses)
        const int gx = gridDim.x;
        const int l = by * gx + bx;
        const int W = gx * 8;
        const int ygrp = l / W;
        const int rem = l - ygrp * W;
        bx = rem >> 3;
        by = ygrp * 8 + (rem & 7);
    }
    const int z = blockIdx.z;
    A  += (long)z * sA;
    Bm += (long)z * sB;
    C  += (long)z * sC;

    const int tid  = threadIdx.x;
    const int wid  = tid >> 6;
    const int lane = tid & 63;
    const int lr = lane & 31;
    const int lh = lane >> 5;
    const int m0 = by * 256;
    const int n0 = bx * 256;
    const int wm = (wid >> 2) * 128;       // wave row: 0 or 128
    const int wn = (wid & 3) * 64;         // wave col: 0,64,128,192

    // staging: one GLDS call covers 64 rows (8 rows/wave, 8 x 16B slots/row).
    // LDS row r slot s holds source k-segment (s ^ (r&7))  [XOR swizzle]
    const int sr = tid >> 3;                         // row within 64-row call
    const int sg = ((tid & 7) ^ (sr & 7)) * 8;       // pre-swizzled source col
    const f16* agS = A  + (long)(m0 + sr) * K + sg;
    const f16* bgS = Bm + (long)(n0 + sr) * K + sg;
    f16* aD = As + wid * (8 * 64);                   // wave-uniform LDS base
    f16* bD = Bs + wid * (8 * 64);

    // fragment read: k-segment g = 2*ks + lh at slot g ^ (row&7)
    const int s7  = lr & 7;
    const int xs0 = ((0 + lh) ^ s7) * 8;
    const int xs1 = ((2 + lh) ^ s7) * 8;
    const int xs2 = ((4 + lh) ^ s7) * 8;
    const int xs3 = ((6 + lh) ^ s7) * 8;
    const f16* aR = As + (wm + lr) * 64;
    const f16* bR = Bs + (wn + lr) * 64;

    f32x16 acc[4][2];
#pragma unroll
    for (int mi = 0; mi < 4; ++mi)
#pragma unroll
        for (int ni = 0; ni < 2; ++ni)
#pragma unroll
            for (int r = 0; r < 16; ++r) acc[mi][ni][r] = 0.f;

    f16x8 b00, b01, b02, b03, b10, b11, b12, b13;

    const int NT = K >> 6;

#define GAc(buf, R0, kt) GLDS(agS + (long)(R0) * K + (kt), aD + (buf) * TSZ + (R0) * 64)
#define GBc(buf, R0, kt) GLDS(bgS + (long)(R0) * K + (kt), bD + (buf) * TSZ + (R0) * 64)

    // prologue: tile0 -> buf0 (B then A = oldest 8), tile1 -> buf1 (B all, A head)
    GBc(0,   0, 0);  GBc(0,  64, 0);  GBc(0, 128, 0);  GBc(0, 192, 0);
    GAc(0,   0, 0);  GAc(0,  64, 0);  GAc(0, 128, 0);  GAc(0, 192, 0);
    GBc(1,   0, 64); GBc(1,  64, 64); GBc(1, 128, 64); GBc(1, 192, 64);
    GAc(1,   0, 64); GAc(1, 128, 64);
    asm volatile("s_waitcnt vmcnt(6)" ::: "memory");   // buf0 fully landed
    __builtin_amdgcn_s_barrier();

#define MFMA8(mi) \
    acc[mi][0] = __builtin_amdgcn_mfma_f32_32x32x16_f16(af0, b00, acc[mi][0], 0, 0, 0); \
    acc[mi][1] = __builtin_amdgcn_mfma_f32_32x32x16_f16(af0, b10, acc[mi][1], 0, 0, 0); \
    acc[mi][0] = __builtin_amdgcn_mfma_f32_32x32x16_f16(af1, b01, acc[mi][0], 0, 0, 0); \
    acc[mi][1] = __builtin_amdgcn_mfma_f32_32x32x16_f16(af1, b11, acc[mi][1], 0, 0, 0); \
    acc[mi][0] = __builtin_amdgcn_mfma_f32_32x32x16_f16(af2, b02, acc[mi][0], 0, 0, 0); \
    acc[mi][1] = __builtin_amdgcn_mfma_f32_32x32x16_f16(af2, b12, acc[mi][1], 0, 0, 0); \
    acc[mi][0] = __builtin_amdgcn_mfma_f32_32x32x16_f16(af3, b03, acc[mi][0], 0, 0, 0); \
    acc[mi][1] = __builtin_amdgcn_mfma_f32_32x32x16_f16(af3, b13, acc[mi][1], 0, 0, 0);

// Phase: frag ds_reads | GLDS issues | barrier | 8 MFMA (compiler inserts
// progressive lgkmcnt per frag dependency) | [vmcnt gate] | barrier
#define PH(buf, mi, VW, ...) { \
    f16x8 af0 = *(const f16x8*)(aR + (buf) * TSZ + (mi) * 2048 + xs0); \
    f16x8 af1 = *(const f16x8*)(aR + (buf) * TSZ + (mi) * 2048 + xs1); \
    f16x8 af2 = *(const f16x8*)(aR + (buf) * TSZ + (mi) * 2048 + xs2); \
    f16x8 af3 = *(const f16x8*)(aR + (buf) * TSZ + (mi) * 2048 + xs3); \
    if ((mi) == 0) { \
        b00 = *(const f16x8*)(bR + (buf) * TSZ + xs0); \
        b01 = *(const f16x8*)(bR + (buf) * TSZ + xs1); \
        b02 = *(const f16x8*)(bR + (buf) * TSZ + xs2); \
        b03 = *(const f16x8*)(bR + (buf) * TSZ + xs3); \
        b10 = *(const f16x8*)(bR + (buf) * TSZ + 2048 + xs0); \
        b11 = *(const f16x8*)(bR + (buf) * TSZ + 2048 + xs1); \
        b12 = *(const f16x8*)(bR + (buf) * TSZ + 2048 + xs2); \
        b13 = *(const f16x8*)(bR + (buf) * TSZ + 2048 + xs3); \
    } \
    __VA_ARGS__ \
    __builtin_amdgcn_s_barrier(); \
    __builtin_amdgcn_s_setprio(1); \
    MFMA8(mi) \
    __builtin_amdgcn_s_setprio(0); \
    if (VW) { asm volatile("s_waitcnt vmcnt(6)" ::: "memory"); } \
    __builtin_amdgcn_s_barrier(); \
}

    for (int i = 0; i < NT / 2; ++i) {
        const long k1 = (long)(2 * i + 1) << 6;                           // tile t+1 (tail)
        const long kA = (2 * i + 2 < NT) ? ((long)(2 * i + 2) << 6) : 0;  // tile t+2
        const long kB = (2 * i + 3 < NT) ? ((long)(2 * i + 3) << 6) : 0;  // tile t+3
        PH(0, 0, 0, GAc(1,  64, k1); GAc(1, 192, k1);)
        PH(0, 1, 0, GBc(0,   0, kA); GBc(0,  64, kA);)
        PH(0, 2, 0, GBc(0, 128, kA); GBc(0, 192, kA);)
        PH(0, 3, 1, GAc(0,   0, kA); GAc(0, 128, kA);)
        PH(1, 0, 0, GAc(0,  64, kA); GAc(0, 192, kA);)
        PH(1, 1, 0, GBc(1,   0, kB); GBc(1,  64, kB);)
        PH(1, 2, 0, GBc(1, 128, kB); GBc(1, 192, kB);)
        PH(1, 3, 1, GAc(1,   0, kB); GAc(1, 128, kB);)
    }

    asm volatile("s_waitcnt vmcnt(0)" ::: "memory");    // drain before LDS dealloc

    // C/D layout (32x32): col = lane&31, row = (reg&3) + 8*(reg>>2) + 4*(lane>>5)
#pragma unroll
    for (int ni = 0; ni < 2; ++ni) {
        const int gc = n0 + wn + ni * 32 + lr;
        const float bv = BIAS ? bias[gc] : 0.0f;
#pragma unroll
        for (int mi = 0; mi < 4; ++mi) {
#pragma unroll
            for (int r = 0; r < 16; ++r) {
                const int row = (r & 3) + 8 * (r >> 2) + 4 * lh;
                const int gr = m0 + wm + mi * 32 + row;
                float v = acc[mi][ni][r] + bv;
                if (RELU) v = fmaxf(v, 0.0f);
                C[(long)gr * N + gc] = (OUT_T)v;
            }
        }
    }
#undef PH
#undef MFMA8
#undef GAc
#undef GBc
}

// ---------------------------------------------------------------------------
// 256x128 tile, BK=64, 512 threads (8 waves 4M x 2N, 64x64 per wave),
// 4-phase K-loop, B through LDS.  LDS 96 KiB, XOR-swizzled.  (Proven R5 form.)
// Now used for the FINAL fused GEMM: out = relu(P . tQt^T) — G4 was removed
// via the softmax row-sum identity  relu(aV.W^T + b) == relu(P.tQ).
// ---------------------------------------------------------------------------
template<typename OUT_T, bool BIAS, bool RELU>
__global__ __launch_bounds__(512, 2)
void gemm_bt3(const f16* __restrict__ A, const f16* __restrict__ Bm,
              OUT_T* __restrict__ C, const float* __restrict__ bias,
              int M, int N, int K, long sA, long sB, long sC)
{
    constexpr int TSA = 256 * 64;
    constexpr int TSB = 128 * 64;
    __shared__ alignas(16) f16 As[2 * TSA];
    __shared__ alignas(16) f16 Bs[2 * TSB];

    int bx = blockIdx.x, by = blockIdx.y;
    {   // XCD-locality remap (gy % 8 == 0 for all uses)
        const int gx = gridDim.x;
        const int l = by * gx + bx;
        const int W = gx * 8;
        const int ygrp = l / W;
        const int rem = l - ygrp * W;
        bx = rem >> 3;
        by = ygrp * 8 + (rem & 7);
    }
    const int z = blockIdx.z;
    A  += (long)z * sA;
    Bm += (long)z * sB;
    C  += (long)z * sC;

    const int tid  = threadIdx.x;
    const int wid  = tid >> 6;
    const int lane = tid & 63;
    const int lr = lane & 31;
    const int lh = lane >> 5;
    const int m0 = by * 256;
    const int n0 = bx * 128;
    const int wm = (wid >> 1) * 64;        // 4 M-waves: 0,64,128,192
    const int wn = (wid & 1) * 64;         // 2 N-waves: 0,64

    const int sr = tid >> 3;
    const int sg = ((tid & 7) ^ (sr & 7)) * 8;
    const f16* agS = A  + (long)(m0 + sr) * K + sg;
    const f16* bgS = Bm + (long)(n0 + sr) * K + sg;
    f16* aD = As + wid * (8 * 64);
    f16* bD = Bs + wid * (8 * 64);

    const int s7  = lr & 7;
    const int xs0 = ((0 + lh) ^ s7) * 8;
    const int xs1 = ((2 + lh) ^ s7) * 8;
    const int xs2 = ((4 + lh) ^ s7) * 8;
    const int xs3 = ((6 + lh) ^ s7) * 8;
    const f16* aR = As + (wm + lr) * 64;
    const f16* bR = Bs + (wn + lr) * 64;

    f32x16 acc[2][2];
#pragma unroll
    for (int mi = 0; mi < 2; ++mi)
#pragma unroll
        for (int ni = 0; ni < 2; ++ni)
#pragma unroll
            for (int r = 0; r < 16; ++r) acc[mi][ni][r] = 0.f;

    f16x8 b00, b01, b02, b03, b10, b11, b12, b13;

    const int NT = K >> 6;

#define GA3(buf, R0, kt) GLDS(agS + (long)(R0) * K + (kt), aD + (buf) * TSA + (R0) * 64)
#define GB3(buf, R0, kt) GLDS(bgS + (long)(R0) * K + (kt), bD + (buf) * TSB + (R0) * 64)

    // prologue: buf0 full (6 = oldest), buf1 B (2).  invariant: 2 outstanding.
    GB3(0,   0, 0);  GB3(0,  64, 0);
    GA3(0,   0, 0);  GA3(0,  64, 0);  GA3(0, 128, 0);  GA3(0, 192, 0);
    GB3(1,   0, 64); GB3(1,  64, 64);
    asm volatile("s_waitcnt vmcnt(2)" ::: "memory");   // buf0 fully landed
    __builtin_amdgcn_s_barrier();

#define MFMA8_3(mi) \
    acc[mi][0] = __builtin_amdgcn_mfma_f32_32x32x16_f16(af0, b00, acc[mi][0], 0, 0, 0); \
    acc[mi][1] = __builtin_amdgcn_mfma_f32_32x32x16_f16(af0, b10, acc[mi][1], 0, 0, 0); \
    acc[mi][0] = __builtin_amdgcn_mfma_f32_32x32x16_f16(af1, b01, acc[mi][0], 0, 0, 0); \
    acc[mi][1] = __builtin_amdgcn_mfma_f32_32x32x16_f16(af1, b11, acc[mi][1], 0, 0, 0); \
    acc[mi][0] = __builtin_amdgcn_mfma_f32_32x32x16_f16(af2, b02, acc[mi][0], 0, 0, 0); \
    acc[mi][1] = __builtin_amdgcn_mfma_f32_32x32x16_f16(af2, b12, acc[mi][1], 0, 0, 0); \
    acc[mi][0] = __builtin_amdgcn_mfma_f32_32x32x16_f16(af3, b03, acc[mi][0], 0, 0, 0); \
    acc[mi][1] = __builtin_amdgcn_mfma_f32_32x32x16_f16(af3, b13, acc[mi][1], 0, 0, 0);

#define PH3(buf, mi, VW, ...) { \
    f16x8 af0 = *(const f16x8*)(aR + (buf) * TSA + (mi) * 2048 + xs0); \
    f16x8 af1 = *(const f16x8*)(aR + (buf) * TSA + (mi) * 2048 + xs1); \
    f16x8 af2 = *(const f16x8*)(aR + (buf) * TSA + (mi) * 2048 + xs2); \
    f16x8 af3 = *(const f16x8*)(aR + (buf) * TSA + (mi) * 2048 + xs3); \
    if ((mi) == 0) { \
        b00 = *(const f16x8*)(bR + (buf) * TSB + xs0); \
        b01 = *(const f16x8*)(bR + (buf) * TSB + xs1); \
        b02 = *(const f16x8*)(bR + (buf) * TSB + xs2); \
        b03 = *(const f16x8*)(bR + (buf) * TSB + xs3); \
        b10 = *(const f16x8*)(bR + (buf) * TSB + 2048 + xs0); \
        b11 = *(const f16x8*)(bR + (buf) * TSB + 2048 + xs1); \
        b12 = *(const f16x8*)(bR + (buf) * TSB + 2048 + xs2); \
        b13 = *(const f16x8*)(bR + (buf) * TSB + 2048 + xs3); \
    } \
    __VA_ARGS__ \
    __builtin_amdgcn_s_barrier(); \
    __builtin_amdgcn_s_setprio(1); \
    MFMA8_3(mi) \
    __builtin_amdgcn_s_setprio(0); \
    if (VW) { asm volatile("s_waitcnt vmcnt(2)" ::: "memory"); } \
    __builtin_amdgcn_s_barrier(); \
}

    for (int i = 0; i < NT / 2; ++i) {
        const long k1 = (long)(2 * i + 1) << 6;                           // tile t+1
        const long kA = (2 * i + 2 < NT) ? ((long)(2 * i + 2) << 6) : 0;  // tile t+2
        const long kB = (2 * i + 3 < NT) ? ((long)(2 * i + 3) << 6) : 0;  // tile t+3
        PH3(0, 0, 0, GA3(1,   0, k1); GA3(1,  64, k1); GA3(1, 128, k1); GA3(1, 192, k1);)
        PH3(0, 1, 1, GB3(0,   0, kA); GB3(0,  64, kA);)
        PH3(1, 0, 0, GA3(0,   0, kA); GA3(0,  64, kA); GA3(0, 128, kA); GA3(0, 192, kA);)
        PH3(1, 1, 1, GB3(1,   0, kB); GB3(1,  64, kB);)
    }

    asm volatile("s_waitcnt vmcnt(0)" ::: "memory");

    // C/D layout (32x32): col = lane&31, row = (reg&3) + 8*(reg>>2) + 4*(lane>>5)
#pragma unroll
    for (int ni = 0; ni < 2; ++ni) {
        const int gc = n0 + wn + ni * 32 + lr;
        const float bv = BIAS ? bias[gc] : 0.0f;
#pragma unroll
        for (int mi = 0; mi < 2; ++mi) {
#pragma unroll
            for (int r = 0; r < 16; ++r) {
                const int row = (r & 3) + 8 * (r >> 2) + 4 * lh;
                const int gr = m0 + wm + mi * 32 + row;
                float v = acc[mi][ni][r] + bv;
                if (RELU) v = fmaxf(v, 0.0f);
                C[(long)gr * N + gc] = (OUT_T)v;
            }
        }
    }
#undef PH3
#undef MFMA8_3
#undef GA3
#undef GB3
}

// ---------------------------------------------------------------------------
__global__ __launch_bounds__(256)
void cast_f32_f16(const float* __restrict__ X, f16* __restrict__ Y)
{
    const long i = ((long)blockIdx.x * 256 + threadIdx.x) * 8;
    float4 a = *(const float4*)(X + i);
    float4 b = *(const float4*)(X + i + 4);
    f16x8 h = {(f16)a.x, (f16)a.y, (f16)a.z, (f16)a.w,
               (f16)b.x, (f16)b.y, (f16)b.z, (f16)b.w};
    *(f16x8*)(Y + i) = h;
}

// f16 [2048 x 1024] per batch -> f16 [1024 x 2048] (LDS 64x64 tile transpose)
__global__ __launch_bounds__(256)
void trans_f16(const f16* __restrict__ X, f16* __restrict__ Y)
{
    __shared__ f16 t[64][72];
    const f16* Xb = X + (long)blockIdx.z * (2048L * 1024);
    f16* Yb = Y + (long)blockIdx.z * (1024L * 2048);
    const int r0 = blockIdx.y * 64;    // q
    const int c0 = blockIdx.x * 64;    // o
    const int tid = threadIdx.x;
    const int tr = tid >> 4;
    const int tc = (tid & 15) * 4;
#pragma unroll
    for (int rr = 0; rr < 64; rr += 16) {
        f16x4 v = *(const f16x4*)(Xb + (long)(r0 + tr + rr) * 1024 + c0 + tc);
        *(f16x4*)&t[tr + rr][tc] = v;
    }
    __syncthreads();
#pragma unroll
    for (int rr = 0; rr < 64; rr += 16) {
        const int orow = tr + rr;
        f16x4 o = {t[tc + 0][orow], t[tc + 1][orow], t[tc + 2][orow], t[tc + 3][orow]};
        *(f16x4*)(Yb + (long)(c0 + orow) * 2048 + r0 + tc) = o;
    }
}

// rowwise softmax over 2048 f16 scores -> fp16 probabilities
__global__ __launch_bounds__(256)
void softmax_ph(const f16* __restrict__ S, f16* __restrict__ P)
{
    const long row = blockIdx.x;
    const f16* s = S + row * 2048;
    f16* p = P + row * 2048;
    const int tid = threadIdx.x;
    const int wid = tid >> 6, lane = tid & 63;

    f16x8 hv = *(const f16x8*)(s + tid * 8);
    float v[8] = {(float)hv[0], (float)hv[1], (float)hv[2], (float)hv[3],
                  (float)hv[4], (float)hv[5], (float)hv[6], (float)hv[7]};

    float m = v[0];
#pragma unroll
    for (int j = 1; j < 8; ++j) m = fmaxf(m, v[j]);
#pragma unroll
    for (int off = 32; off > 0; off >>= 1) m = fmaxf(m, __shfl_xor(m, off, 64));

    __shared__ float red[8];
    if (lane == 0) red[wid] = m;
    __syncthreads();
    m = fmaxf(fmaxf(red[0], red[1]), fmaxf(red[2], red[3]));

    float sum = 0.f;
#pragma unroll
    for (int j = 0; j < 8; ++j) { v[j] = __expf(v[j] - m); sum += v[j]; }
#pragma unroll
    for (int off = 32; off > 0; off >>= 1) sum += __shfl_xor(sum, off, 64);
    if (lane == 0) red[4 + wid] = sum;
    __syncthreads();
    sum = red[4] + red[5] + red[6] + red[7];

    const float inv = 1.0f / sum;
    f16x8 h = {(f16)(v[0] * inv), (f16)(v[1] * inv), (f16)(v[2] * inv), (f16)(v[3] * inv),
               (f16)(v[4] * inv), (f16)(v[5] * inv), (f16)(v[6] * inv), (f16)(v[7] * inv)};
    *(f16x8*)(p + tid * 8) = h;
}

// ---------------------------------------------------------------------------
extern "C" void kernel_launch(void* const* d_in, const int* in_sizes, int n_in,
                              void* d_out, int out_size, void* d_ws, size_t ws_size,
                              hipStream_t stream)
{
    const float* proj_p = (const float*)d_in[0];  // [16,2048,1024]
    const float* proj_q = (const float*)d_in[1];  // [16,2048,1024]
    const float* W      = (const float*)d_in[2];  // [1024,1024]
    const float* bias   = (const float*)d_in[3];  // [1024]
    float* out = (float*)d_out;

    constexpr long Bc = 16, L = 2048, H = 1024, NB = 4;
    constexpr long nPQ = Bc * L * H;              // 33,554,432 elements

    char* ws = (char*)d_ws;
    f16*   pB  = (f16*)(ws + 0L);                 // 67,108,864 B
    f16*   qB  = (f16*)(ws + 67108864L);          // 67,108,864 B
    f16*   tQ  = (f16*)(ws + 134217728L);         // 67,108,864 B  [B*L][H]
    f16*   tQt = (f16*)(ws + 201326592L);         // 67,108,864 B  [B][H][L]
    f16*   Wb  = (f16*)(ws + 268435456L);         //  2,097,152 B
    f16*   Sh  = (f16*)(ws + 270532608L);         // 33,554,432 B (4 batches f16)
    f16*   P   = (f16*)(ws + 304087040L);         // 33,554,432 B (4 batches f16)
    // total ws use: 337,641,472 B

    cast_f32_f16<<<nPQ / (256 * 8), 256, 0, stream>>>(proj_p, pB);
    cast_f32_f16<<<(H * H) / (256 * 8), 256, 0, stream>>>(W, Wb);
    cast_f32_f16<<<nPQ / (256 * 8), 256, 0, stream>>>(proj_q, qB);

    // G1: tQ[b,q,o] = qB[b,q,:] . Wb[o,:] + bias[o]   (256-tile 8-phase)
    gemm_bt2<f16, true, false><<<dim3(H / 256, (Bc * L) / 256, 1), 512, 0, stream>>>(
        qB, Wb, tQ, bias, (int)(Bc * L), (int)H, (int)H, 0, 0, 0);

    // tQt[b][o][q] = tQ[b*L+q][o]   (for the final out = relu(P . tQ) GEMM)
    trans_f16<<<dim3(16, 32, 16), 256, 0, stream>>>(tQ, tQt);

    for (int c = 0; c < 4; ++c) {
        const long boff = (long)c * NB * L * H;
        // G2: S[p,q] = pB[p,:] . tQ[q,:]   (f16 out, 256-tile 8-phase)
        gemm_bt2<f16, false, false><<<dim3(L / 256, L / 256, NB), 512, 0, stream>>>(
            pB + boff, tQ + boff, Sh, nullptr, (int)L, (int)L, (int)H,
            L * H, L * H, L * L);
        // softmax rows (f16 in) -> P f16
        softmax_ph<<<NB * L, 256, 0, stream>>>(Sh, P);
        // G3': out[p,o] = relu( P[p,:] . tQt[o,:] )   — replaces old G3+G4
        //      (softmax rows sum to 1, so P.tQ == aV.W^T + b exactly)
        gemm_bt3<float, false, true><<<dim3(H / 128, L / 256, NB), 512, 0, stream>>>(
            P, tQt + (long)c * NB * H * L, out + boff, nullptr,
            (int)L, (int)H, (int)L, L * L, H * L, L * H);
    }
}

// Round 9
// 841.930 us; speedup vs baseline: 1.1455x; 1.0080x over previous
//
#include <hip/hip_runtime.h>

typedef _Float16 f16;
typedef _Float16 f16x8 __attribute__((ext_vector_type(8)));
typedef _Float16 f16x4 __attribute__((ext_vector_type(4)));
typedef float    f32x16 __attribute__((ext_vector_type(16)));

#define GLDS(gp, lp) __builtin_amdgcn_global_load_lds( \
    (const __attribute__((address_space(1))) void*)(gp), \
    (__attribute__((address_space(3))) void*)(lp), 16, 0, 0)

// ---------------------------------------------------------------------------
// 256x256 tile, BK=64, 512 threads (8 waves 2x4, 128x64 per wave), 8-phase
// K-loop with counted vmcnt(6) prefetch, LDS XOR-swizzle, s_setprio around
// MFMA clusters.  Double-buffered 128 KiB LDS.  (Proven R5/R7 form.)
// ---------------------------------------------------------------------------
template<typename OUT_T, bool BIAS, bool RELU>
__global__ __launch_bounds__(512, 2)
void gemm_bt2(const f16* __restrict__ A, const f16* __restrict__ Bm,
              OUT_T* __restrict__ C, const float* __restrict__ bias,
              int M, int N, int K, long sA, long sB, long sC)
{
    constexpr int TSZ = 256 * 64;          // f16 elements per tile buffer
    __shared__ alignas(16) f16 As[2 * TSZ];
    __shared__ alignas(16) f16 Bs[2 * TSZ];

    int bx = blockIdx.x, by = blockIdx.y;
    {   // XCD-locality remap (gy % 8 == 0 for all uses)
        const int gx = gridDim.x;
        const int l = by * gx + bx;
        const int W = gx * 8;
        const int ygrp = l / W;
        const int rem = l - ygrp * W;
        bx = rem >> 3;
        by = ygrp * 8 + (rem & 7);
    }
    const int z = blockIdx.z;
    A  += (long)z * sA;
    Bm += (long)z * sB;
    C  += (long)z * sC;

    const int tid  = threadIdx.x;
    const int wid  = tid >> 6;
    const int lane = tid & 63;
    const int lr = lane & 31;
    const int lh = lane >> 5;
    const int m0 = by * 256;
    const int n0 = bx * 256;
    const int wm = (wid >> 2) * 128;       // wave row: 0 or 128
    const int wn = (wid & 3) * 64;         // wave col: 0,64,128,192

    // staging: one GLDS call covers 64 rows (8 rows/wave, 8 x 16B slots/row).
    // LDS row r slot s holds source k-segment (s ^ (r&7))  [XOR swizzle]
    const int sr = tid >> 3;                         // row within 64-row call
    const int sg = ((tid & 7) ^ (sr & 7)) * 8;       // pre-swizzled source col
    const f16* agS = A  + (long)(m0 + sr) * K + sg;
    const f16* bgS = Bm + (long)(n0 + sr) * K + sg;
    f16* aD = As + wid * (8 * 64);                   // wave-uniform LDS base
    f16* bD = Bs + wid * (8 * 64);

    // fragment read: k-segment g = 2*ks + lh at slot g ^ (row&7)
    const int s7  = lr & 7;
    const int xs0 = ((0 + lh) ^ s7) * 8;
    const int xs1 = ((2 + lh) ^ s7) * 8;
    const int xs2 = ((4 + lh) ^ s7) * 8;
    const int xs3 = ((6 + lh) ^ s7) * 8;
    const f16* aR = As + (wm + lr) * 64;
    const f16* bR = Bs + (wn + lr) * 64;

    f32x16 acc[4][2];
#pragma unroll
    for (int mi = 0; mi < 4; ++mi)
#pragma unroll
        for (int ni = 0; ni < 2; ++ni)
#pragma unroll
            for (int r = 0; r < 16; ++r) acc[mi][ni][r] = 0.f;

    f16x8 b00, b01, b02, b03, b10, b11, b12, b13;

    const int NT = K >> 6;

#define GAc(buf, R0, kt) GLDS(agS + (long)(R0) * K + (kt), aD + (buf) * TSZ + (R0) * 64)
#define GBc(buf, R0, kt) GLDS(bgS + (long)(R0) * K + (kt), bD + (buf) * TSZ + (R0) * 64)

    // prologue: tile0 -> buf0 (B then A = oldest 8), tile1 -> buf1 (B all, A head)
    GBc(0,   0, 0);  GBc(0,  64, 0);  GBc(0, 128, 0);  GBc(0, 192, 0);
    GAc(0,   0, 0);  GAc(0,  64, 0);  GAc(0, 128, 0);  GAc(0, 192, 0);
    GBc(1,   0, 64); GBc(1,  64, 64); GBc(1, 128, 64); GBc(1, 192, 64);
    GAc(1,   0, 64); GAc(1, 128, 64);
    asm volatile("s_waitcnt vmcnt(6)" ::: "memory");   // buf0 fully landed
    __builtin_amdgcn_s_barrier();

#define MFMA8(mi) \
    acc[mi][0] = __builtin_amdgcn_mfma_f32_32x32x16_f16(af0, b00, acc[mi][0], 0, 0, 0); \
    acc[mi][1] = __builtin_amdgcn_mfma_f32_32x32x16_f16(af0, b10, acc[mi][1], 0, 0, 0); \
    acc[mi][0] = __builtin_amdgcn_mfma_f32_32x32x16_f16(af1, b01, acc[mi][0], 0, 0, 0); \
    acc[mi][1] = __builtin_amdgcn_mfma_f32_32x32x16_f16(af1, b11, acc[mi][1], 0, 0, 0); \
    acc[mi][0] = __builtin_amdgcn_mfma_f32_32x32x16_f16(af2, b02, acc[mi][0], 0, 0, 0); \
    acc[mi][1] = __builtin_amdgcn_mfma_f32_32x32x16_f16(af2, b12, acc[mi][1], 0, 0, 0); \
    acc[mi][0] = __builtin_amdgcn_mfma_f32_32x32x16_f16(af3, b03, acc[mi][0], 0, 0, 0); \
    acc[mi][1] = __builtin_amdgcn_mfma_f32_32x32x16_f16(af3, b13, acc[mi][1], 0, 0, 0);

// Phase: frag ds_reads | GLDS issues | barrier | 8 MFMA (compiler inserts
// progressive lgkmcnt per frag dependency) | [vmcnt gate] | barrier
#define PH(buf, mi, VW, ...) { \
    f16x8 af0 = *(const f16x8*)(aR + (buf) * TSZ + (mi) * 2048 + xs0); \
    f16x8 af1 = *(const f16x8*)(aR + (buf) * TSZ + (mi) * 2048 + xs1); \
    f16x8 af2 = *(const f16x8*)(aR + (buf) * TSZ + (mi) * 2048 + xs2); \
    f16x8 af3 = *(const f16x8*)(aR + (buf) * TSZ + (mi) * 2048 + xs3); \
    if ((mi) == 0) { \
        b00 = *(const f16x8*)(bR + (buf) * TSZ + xs0); \
        b01 = *(const f16x8*)(bR + (buf) * TSZ + xs1); \
        b02 = *(const f16x8*)(bR + (buf) * TSZ + xs2); \
        b03 = *(const f16x8*)(bR + (buf) * TSZ + xs3); \
        b10 = *(const f16x8*)(bR + (buf) * TSZ + 2048 + xs0); \
        b11 = *(const f16x8*)(bR + (buf) * TSZ + 2048 + xs1); \
        b12 = *(const f16x8*)(bR + (buf) * TSZ + 2048 + xs2); \
        b13 = *(const f16x8*)(bR + (buf) * TSZ + 2048 + xs3); \
    } \
    __VA_ARGS__ \
    __builtin_amdgcn_s_barrier(); \
    __builtin_amdgcn_s_setprio(1); \
    MFMA8(mi) \
    __builtin_amdgcn_s_setprio(0); \
    if (VW) { asm volatile("s_waitcnt vmcnt(6)" ::: "memory"); } \
    __builtin_amdgcn_s_barrier(); \
}

    for (int i = 0; i < NT / 2; ++i) {
        const long k1 = (long)(2 * i + 1) << 6;                           // tile t+1 (tail)
        const long kA = (2 * i + 2 < NT) ? ((long)(2 * i + 2) << 6) : 0;  // tile t+2
        const long kB = (2 * i + 3 < NT) ? ((long)(2 * i + 3) << 6) : 0;  // tile t+3
        PH(0, 0, 0, GAc(1,  64, k1); GAc(1, 192, k1);)
        PH(0, 1, 0, GBc(0,   0, kA); GBc(0,  64, kA);)
        PH(0, 2, 0, GBc(0, 128, kA); GBc(0, 192, kA);)
        PH(0, 3, 1, GAc(0,   0, kA); GAc(0, 128, kA);)
        PH(1, 0, 0, GAc(0,  64, kA); GAc(0, 192, kA);)
        PH(1, 1, 0, GBc(1,   0, kB); GBc(1,  64, kB);)
        PH(1, 2, 0, GBc(1, 128, kB); GBc(1, 192, kB);)
        PH(1, 3, 1, GAc(1,   0, kB); GAc(1, 128, kB);)
    }

    asm volatile("s_waitcnt vmcnt(0)" ::: "memory");    // drain before LDS dealloc

    // C/D layout (32x32): col = lane&31, row = (reg&3) + 8*(reg>>2) + 4*(lane>>5)
#pragma unroll
    for (int ni = 0; ni < 2; ++ni) {
        const int gc = n0 + wn + ni * 32 + lr;
        const float bv = BIAS ? bias[gc] : 0.0f;
#pragma unroll
        for (int mi = 0; mi < 4; ++mi) {
#pragma unroll
            for (int r = 0; r < 16; ++r) {
                const int row = (r & 3) + 8 * (r >> 2) + 4 * lh;
                const int gr = m0 + wm + mi * 32 + row;
                float v = acc[mi][ni][r] + bv;
                if (RELU) v = fmaxf(v, 0.0f);
                C[(long)gr * N + gc] = (OUT_T)v;
            }
        }
    }
#undef PH
#undef MFMA8
#undef GAc
#undef GBc
}

// ---------------------------------------------------------------------------
// 256x128 tile, BK=64, 512 threads (8 waves 4M x 2N, 64x64 per wave),
// 4-phase K-loop, B through LDS.  LDS 96 KiB, XOR-swizzled.  (Proven R5 form.)
// Used for the FINAL fused GEMM: out = relu(P . tQt^T).
// ---------------------------------------------------------------------------
template<typename OUT_T, bool BIAS, bool RELU>
__global__ __launch_bounds__(512, 2)
void gemm_bt3(const f16* __restrict__ A, const f16* __restrict__ Bm,
              OUT_T* __restrict__ C, const float* __restrict__ bias,
              int M, int N, int K, long sA, long sB, long sC)
{
    constexpr int TSA = 256 * 64;
    constexpr int TSB = 128 * 64;
    __shared__ alignas(16) f16 As[2 * TSA];
    __shared__ alignas(16) f16 Bs[2 * TSB];

    int bx = blockIdx.x, by = blockIdx.y;
    {   // XCD-locality remap (gy % 8 == 0 for all uses)
        const int gx = gridDim.x;
        const int l = by * gx + bx;
        const int W = gx * 8;
        const int ygrp = l / W;
        const int rem = l - ygrp * W;
        bx = rem >> 3;
        by = ygrp * 8 + (rem & 7);
    }
    const int z = blockIdx.z;
    A  += (long)z * sA;
    Bm += (long)z * sB;
    C  += (long)z * sC;

    const int tid  = threadIdx.x;
    const int wid  = tid >> 6;
    const int lane = tid & 63;
    const int lr = lane & 31;
    const int lh = lane >> 5;
    const int m0 = by * 256;
    const int n0 = bx * 128;
    const int wm = (wid >> 1) * 64;        // 4 M-waves: 0,64,128,192
    const int wn = (wid & 1) * 64;         // 2 N-waves: 0,64

    const int sr = tid >> 3;
    const int sg = ((tid & 7) ^ (sr & 7)) * 8;
    const f16* agS = A  + (long)(m0 + sr) * K + sg;
    const f16* bgS = Bm + (long)(n0 + sr) * K + sg;
    f16* aD = As + wid * (8 * 64);
    f16* bD = Bs + wid * (8 * 64);

    const int s7  = lr & 7;
    const int xs0 = ((0 + lh) ^ s7) * 8;
    const int xs1 = ((2 + lh) ^ s7) * 8;
    const int xs2 = ((4 + lh) ^ s7) * 8;
    const int xs3 = ((6 + lh) ^ s7) * 8;
    const f16* aR = As + (wm + lr) * 64;
    const f16* bR = Bs + (wn + lr) * 64;

    f32x16 acc[2][2];
#pragma unroll
    for (int mi = 0; mi < 2; ++mi)
#pragma unroll
        for (int ni = 0; ni < 2; ++ni)
#pragma unroll
            for (int r = 0; r < 16; ++r) acc[mi][ni][r] = 0.f;

    f16x8 b00, b01, b02, b03, b10, b11, b12, b13;

    const int NT = K >> 6;

#define GA3(buf, R0, kt) GLDS(agS + (long)(R0) * K + (kt), aD + (buf) * TSA + (R0) * 64)
#define GB3(buf, R0, kt) GLDS(bgS + (long)(R0) * K + (kt), bD + (buf) * TSB + (R0) * 64)

    // prologue: buf0 full (6 = oldest), buf1 B (2).  invariant: 2 outstanding.
    GB3(0,   0, 0);  GB3(0,  64, 0);
    GA3(0,   0, 0);  GA3(0,  64, 0);  GA3(0, 128, 0);  GA3(0, 192, 0);
    GB3(1,   0, 64); GB3(1,  64, 64);
    asm volatile("s_waitcnt vmcnt(2)" ::: "memory");   // buf0 fully landed
    __builtin_amdgcn_s_barrier();

#define MFMA8_3(mi) \
    acc[mi][0] = __builtin_amdgcn_mfma_f32_32x32x16_f16(af0, b00, acc[mi][0], 0, 0, 0); \
    acc[mi][1] = __builtin_amdgcn_mfma_f32_32x32x16_f16(af0, b10, acc[mi][1], 0, 0, 0); \
    acc[mi][0] = __builtin_amdgcn_mfma_f32_32x32x16_f16(af1, b01, acc[mi][0], 0, 0, 0); \
    acc[mi][1] = __builtin_amdgcn_mfma_f32_32x32x16_f16(af1, b11, acc[mi][1], 0, 0, 0); \
    acc[mi][0] = __builtin_amdgcn_mfma_f32_32x32x16_f16(af2, b02, acc[mi][0], 0, 0, 0); \
    acc[mi][1] = __builtin_amdgcn_mfma_f32_32x32x16_f16(af2, b12, acc[mi][1], 0, 0, 0); \
    acc[mi][0] = __builtin_amdgcn_mfma_f32_32x32x16_f16(af3, b03, acc[mi][0], 0, 0, 0); \
    acc[mi][1] = __builtin_amdgcn_mfma_f32_32x32x16_f16(af3, b13, acc[mi][1], 0, 0, 0);

#define PH3(buf, mi, VW, ...) { \
    f16x8 af0 = *(const f16x8*)(aR + (buf) * TSA + (mi) * 2048 + xs0); \
    f16x8 af1 = *(const f16x8*)(aR + (buf) * TSA + (mi) * 2048 + xs1); \
    f16x8 af2 = *(const f16x8*)(aR + (buf) * TSA + (mi) * 2048 + xs2); \
    f16x8 af3 = *(const f16x8*)(aR + (buf) * TSA + (mi) * 2048 + xs3); \
    if ((mi) == 0) { \
        b00 = *(const f16x8*)(bR + (buf) * TSB + xs0); \
        b01 = *(const f16x8*)(bR + (buf) * TSB + xs1); \
        b02 = *(const f16x8*)(bR + (buf) * TSB + xs2); \
        b03 = *(const f16x8*)(bR + (buf) * TSB + xs3); \
        b10 = *(const f16x8*)(bR + (buf) * TSB + 2048 + xs0); \
        b11 = *(const f16x8*)(bR + (buf) * TSB + 2048 + xs1); \
        b12 = *(const f16x8*)(bR + (buf) * TSB + 2048 + xs2); \
        b13 = *(const f16x8*)(bR + (buf) * TSB + 2048 + xs3); \
    } \
    __VA_ARGS__ \
    __builtin_amdgcn_s_barrier(); \
    __builtin_amdgcn_s_setprio(1); \
    MFMA8_3(mi) \
    __builtin_amdgcn_s_setprio(0); \
    if (VW) { asm volatile("s_waitcnt vmcnt(2)" ::: "memory"); } \
    __builtin_amdgcn_s_barrier(); \
}

    for (int i = 0; i < NT / 2; ++i) {
        const long k1 = (long)(2 * i + 1) << 6;                           // tile t+1
        const long kA = (2 * i + 2 < NT) ? ((long)(2 * i + 2) << 6) : 0;  // tile t+2
        const long kB = (2 * i + 3 < NT) ? ((long)(2 * i + 3) << 6) : 0;  // tile t+3
        PH3(0, 0, 0, GA3(1,   0, k1); GA3(1,  64, k1); GA3(1, 128, k1); GA3(1, 192, k1);)
        PH3(0, 1, 1, GB3(0,   0, kA); GB3(0,  64, kA);)
        PH3(1, 0, 0, GA3(0,   0, kA); GA3(0,  64, kA); GA3(0, 128, kA); GA3(0, 192, kA);)
        PH3(1, 1, 1, GB3(1,   0, kB); GB3(1,  64, kB);)
    }

    asm volatile("s_waitcnt vmcnt(0)" ::: "memory");

    // C/D layout (32x32): col = lane&31, row = (reg&3) + 8*(reg>>2) + 4*(lane>>5)
#pragma unroll
    for (int ni = 0; ni < 2; ++ni) {
        const int gc = n0 + wn + ni * 32 + lr;
        const float bv = BIAS ? bias[gc] : 0.0f;
#pragma unroll
        for (int mi = 0; mi < 2; ++mi) {
#pragma unroll
            for (int r = 0; r < 16; ++r) {
                const int row = (r & 3) + 8 * (r >> 2) + 4 * lh;
                const int gr = m0 + wm + mi * 32 + row;
                float v = acc[mi][ni][r] + bv;
                if (RELU) v = fmaxf(v, 0.0f);
                C[(long)gr * N + gc] = (OUT_T)v;
            }
        }
    }
#undef PH3
#undef MFMA8_3
#undef GA3
#undef GB3
}

// ---------------------------------------------------------------------------
// Fused cast: proj_p -> pB (blocks [0,16384)), proj_q -> qB ([16384,32768)),
// W -> Wb ([32768, 33280)).  One launch instead of three.
__global__ __launch_bounds__(256)
void cast_all(const float* __restrict__ Xp, const float* __restrict__ Xq,
              const float* __restrict__ Xw, f16* __restrict__ Yp,
              f16* __restrict__ Yq, f16* __restrict__ Yw)
{
    const long b = blockIdx.x;
    const float* X;
    f16* Y;
    long off;
    if (b < 16384)      { X = Xp; Y = Yp; off = b; }
    else if (b < 32768) { X = Xq; Y = Yq; off = b - 16384; }
    else                { X = Xw; Y = Yw; off = b - 32768; }
    const long i = (off * 256 + threadIdx.x) * 8;
    float4 a = *(const float4*)(X + i);
    float4 c = *(const float4*)(X + i + 4);
    f16x8 h = {(f16)a.x, (f16)a.y, (f16)a.z, (f16)a.w,
               (f16)c.x, (f16)c.y, (f16)c.z, (f16)c.w};
    *(f16x8*)(Y + i) = h;
}

// f16 [2048 x 1024] per batch -> f16 [1024 x 2048] (LDS 64x64 tile transpose)
__global__ __launch_bounds__(256)
void trans_f16(const f16* __restrict__ X, f16* __restrict__ Y)
{
    __shared__ f16 t[64][72];
    const f16* Xb = X + (long)blockIdx.z * (2048L * 1024);
    f16* Yb = Y + (long)blockIdx.z * (1024L * 2048);
    const int r0 = blockIdx.y * 64;    // q
    const int c0 = blockIdx.x * 64;    // o
    const int tid = threadIdx.x;
    const int tr = tid >> 4;
    const int tc = (tid & 15) * 4;
#pragma unroll
    for (int rr = 0; rr < 64; rr += 16) {
        f16x4 v = *(const f16x4*)(Xb + (long)(r0 + tr + rr) * 1024 + c0 + tc);
        *(f16x4*)&t[tr + rr][tc] = v;
    }
    __syncthreads();
#pragma unroll
    for (int rr = 0; rr < 64; rr += 16) {
        const int orow = tr + rr;
        f16x4 o = {t[tc + 0][orow], t[tc + 1][orow], t[tc + 2][orow], t[tc + 3][orow]};
        *(f16x4*)(Yb + (long)(c0 + orow) * 2048 + r0 + tc) = o;
    }
}

// rowwise softmax over 2048 f16 scores -> fp16 probabilities
__global__ __launch_bounds__(256)
void softmax_ph(const f16* __restrict__ S, f16* __restrict__ P)
{
    const long row = blockIdx.x;
    const f16* s = S + row * 2048;
    f16* p = P + row * 2048;
    const int tid = threadIdx.x;
    const int wid = tid >> 6, lane = tid & 63;

    f16x8 hv = *(const f16x8*)(s + tid * 8);
    float v[8] = {(float)hv[0], (float)hv[1], (float)hv[2], (float)hv[3],
                  (float)hv[4], (float)hv[5], (float)hv[6], (float)hv[7]};

    float m = v[0];
#pragma unroll
    for (int j = 1; j < 8; ++j) m = fmaxf(m, v[j]);
#pragma unroll
    for (int off = 32; off > 0; off >>= 1) m = fmaxf(m, __shfl_xor(m, off, 64));

    __shared__ float red[8];
    if (lane == 0) red[wid] = m;
    __syncthreads();
    m = fmaxf(fmaxf(red[0], red[1]), fmaxf(red[2], red[3]));

    float sum = 0.f;
#pragma unroll
    for (int j = 0; j < 8; ++j) { v[j] = __expf(v[j] - m); sum += v[j]; }
#pragma unroll
    for (int off = 32; off > 0; off >>= 1) sum += __shfl_xor(sum, off, 64);
    if (lane == 0) red[4 + wid] = sum;
    __syncthreads();
    sum = red[4] + red[5] + red[6] + red[7];

    const float inv = 1.0f / sum;
    f16x8 h = {(f16)(v[0] * inv), (f16)(v[1] * inv), (f16)(v[2] * inv), (f16)(v[3] * inv),
               (f16)(v[4] * inv), (f16)(v[5] * inv), (f16)(v[6] * inv), (f16)(v[7] * inv)};
    *(f16x8*)(p + tid * 8) = h;
}

// ---------------------------------------------------------------------------
extern "C" void kernel_launch(void* const* d_in, const int* in_sizes, int n_in,
                              void* d_out, int out_size, void* d_ws, size_t ws_size,
                              hipStream_t stream)
{
    const float* proj_p = (const float*)d_in[0];  // [16,2048,1024]
    const float* proj_q = (const float*)d_in[1];  // [16,2048,1024]
    const float* W      = (const float*)d_in[2];  // [1024,1024]
    const float* bias   = (const float*)d_in[3];  // [1024]
    float* out = (float*)d_out;

    constexpr long Bc = 16, L = 2048, H = 1024;

    // Workspace layout (single-chunk, z=16 everywhere).  Liveness overlay:
    //   P (128 MB) overlays pB+qB — pB dead after G2, qB dead after G1,
    //   softmax (the writer of P) runs strictly after G2 on this stream.
    // Total footprint 404,750,336 B  (< 438,304,768 B proven in use at R0).
    char* ws = (char*)d_ws;
    f16*   pB  = (f16*)(ws + 0L);                 // 67,108,864 B
    f16*   qB  = (f16*)(ws + 67108864L);          // 67,108,864 B
    f16*   tQ  = (f16*)(ws + 134217728L);         // 67,108,864 B  [B*L][H]
    f16*   tQt = (f16*)(ws + 201326592L);         // 67,108,864 B  [B][H][L]
    f16*   Wb  = (f16*)(ws + 268435456L);         //  2,097,152 B
    f16*   Sh  = (f16*)(ws + 270532608L);         // 134,217,728 B (16 batches f16)
    f16*   P   = (f16*)(ws + 0L);                 // 134,217,728 B (overlay pB+qB)

    // 1. all input casts in one launch
    cast_all<<<33280, 256, 0, stream>>>(proj_p, proj_q, W, pB, qB, Wb);

    // 2. G1: tQ[b,q,o] = qB[b,q,:] . Wb[o,:] + bias[o]   (256-tile 8-phase)
    gemm_bt2<f16, true, false><<<dim3(H / 256, (Bc * L) / 256, 1), 512, 0, stream>>>(
        qB, Wb, tQ, bias, (int)(Bc * L), (int)H, (int)H, 0, 0, 0);

    // 3. tQt[b][o][q] = tQ[b*L+q][o]
    trans_f16<<<dim3(16, 32, 16), 256, 0, stream>>>(tQ, tQt);

    // 4. G2: Sh[b][p,q] = pB[b][p,:] . tQ[b][q,:]   (f16 out, all 16 batches)
    gemm_bt2<f16, false, false><<<dim3(L / 256, L / 256, (int)Bc), 512, 0, stream>>>(
        pB, tQ, Sh, nullptr, (int)L, (int)L, (int)H, L * H, L * H, L * L);

    // 5. softmax rows (f16 in) -> P f16   (P overlays pB/qB — both dead now)
    softmax_ph<<<(int)(Bc * L), 256, 0, stream>>>(Sh, P);

    // 6. G3': out[b][p,o] = relu( P[b][p,:] . tQt[b][o,:] )
    gemm_bt3<float, false, true><<<dim3(H / 128, L / 256, (int)Bc), 512, 0, stream>>>(
        P, tQt, out, nullptr, (int)L, (int)H, (int)L, L * L, H * L, L * H);
}

// Round 10
// 799.798 us; speedup vs baseline: 1.2059x; 1.0527x over previous
//
#include <hip/hip_runtime.h>

typedef _Float16 f16;
typedef _Float16 f16x8 __attribute__((ext_vector_type(8)));
typedef _Float16 f16x4 __attribute__((ext_vector_type(4)));
typedef float    f32x16 __attribute__((ext_vector_type(16)));

#define GLDS(gp, lp) __builtin_amdgcn_global_load_lds( \
    (const __attribute__((address_space(1))) void*)(gp), \
    (__attribute__((address_space(3))) void*)(lp), 16, 0, 0)

// ---------------------------------------------------------------------------
// 256x256 tile, BK=64, 512 threads (8 waves 2x4, 128x64 per wave), 8-phase
// K-loop with counted vmcnt(6) prefetch, LDS XOR-swizzle, s_setprio around
// MFMA clusters.  Double-buffered 128 KiB LDS.  (Proven R5/R7 form; 808 TF
// measured on the G1 shape.)  Now used for ALL three GEMMs — at z=16 every
// grid is >= 2 full 256-CU rounds, so the 256x128 variant is obsolete.
// ---------------------------------------------------------------------------
template<typename OUT_T, bool BIAS, bool RELU>
__global__ __launch_bounds__(512, 2)
void gemm_bt2(const f16* __restrict__ A, const f16* __restrict__ Bm,
              OUT_T* __restrict__ C, const float* __restrict__ bias,
              int M, int N, int K, long sA, long sB, long sC)
{
    constexpr int TSZ = 256 * 64;          // f16 elements per tile buffer
    __shared__ alignas(16) f16 As[2 * TSZ];
    __shared__ alignas(16) f16 Bs[2 * TSZ];

    int bx = blockIdx.x, by = blockIdx.y;
    {   // XCD-locality remap (gy % 8 == 0 for all uses)
        const int gx = gridDim.x;
        const int l = by * gx + bx;
        const int W = gx * 8;
        const int ygrp = l / W;
        const int rem = l - ygrp * W;
        bx = rem >> 3;
        by = ygrp * 8 + (rem & 7);
    }
    const int z = blockIdx.z;
    A  += (long)z * sA;
    Bm += (long)z * sB;
    C  += (long)z * sC;

    const int tid  = threadIdx.x;
    const int wid  = tid >> 6;
    const int lane = tid & 63;
    const int lr = lane & 31;
    const int lh = lane >> 5;
    const int m0 = by * 256;
    const int n0 = bx * 256;
    const int wm = (wid >> 2) * 128;       // wave row: 0 or 128
    const int wn = (wid & 3) * 64;         // wave col: 0,64,128,192

    // staging: one GLDS call covers 64 rows (8 rows/wave, 8 x 16B slots/row).
    // LDS row r slot s holds source k-segment (s ^ (r&7))  [XOR swizzle]
    const int sr = tid >> 3;                         // row within 64-row call
    const int sg = ((tid & 7) ^ (sr & 7)) * 8;       // pre-swizzled source col
    const f16* agS = A  + (long)(m0 + sr) * K + sg;
    const f16* bgS = Bm + (long)(n0 + sr) * K + sg;
    f16* aD = As + wid * (8 * 64);                   // wave-uniform LDS base
    f16* bD = Bs + wid * (8 * 64);

    // fragment read: k-segment g = 2*ks + lh at slot g ^ (row&7)
    const int s7  = lr & 7;
    const int xs0 = ((0 + lh) ^ s7) * 8;
    const int xs1 = ((2 + lh) ^ s7) * 8;
    const int xs2 = ((4 + lh) ^ s7) * 8;
    const int xs3 = ((6 + lh) ^ s7) * 8;
    const f16* aR = As + (wm + lr) * 64;
    const f16* bR = Bs + (wn + lr) * 64;

    f32x16 acc[4][2];
#pragma unroll
    for (int mi = 0; mi < 4; ++mi)
#pragma unroll
        for (int ni = 0; ni < 2; ++ni)
#pragma unroll
            for (int r = 0; r < 16; ++r) acc[mi][ni][r] = 0.f;

    f16x8 b00, b01, b02, b03, b10, b11, b12, b13;

    const int NT = K >> 6;

#define GAc(buf, R0, kt) GLDS(agS + (long)(R0) * K + (kt), aD + (buf) * TSZ + (R0) * 64)
#define GBc(buf, R0, kt) GLDS(bgS + (long)(R0) * K + (kt), bD + (buf) * TSZ + (R0) * 64)

    // prologue: tile0 -> buf0 (B then A = oldest 8), tile1 -> buf1 (B all, A head)
    GBc(0,   0, 0);  GBc(0,  64, 0);  GBc(0, 128, 0);  GBc(0, 192, 0);
    GAc(0,   0, 0);  GAc(0,  64, 0);  GAc(0, 128, 0);  GAc(0, 192, 0);
    GBc(1,   0, 64); GBc(1,  64, 64); GBc(1, 128, 64); GBc(1, 192, 64);
    GAc(1,   0, 64); GAc(1, 128, 64);
    asm volatile("s_waitcnt vmcnt(6)" ::: "memory");   // buf0 fully landed
    __builtin_amdgcn_s_barrier();

#define MFMA8(mi) \
    acc[mi][0] = __builtin_amdgcn_mfma_f32_32x32x16_f16(af0, b00, acc[mi][0], 0, 0, 0); \
    acc[mi][1] = __builtin_amdgcn_mfma_f32_32x32x16_f16(af0, b10, acc[mi][1], 0, 0, 0); \
    acc[mi][0] = __builtin_amdgcn_mfma_f32_32x32x16_f16(af1, b01, acc[mi][0], 0, 0, 0); \
    acc[mi][1] = __builtin_amdgcn_mfma_f32_32x32x16_f16(af1, b11, acc[mi][1], 0, 0, 0); \
    acc[mi][0] = __builtin_amdgcn_mfma_f32_32x32x16_f16(af2, b02, acc[mi][0], 0, 0, 0); \
    acc[mi][1] = __builtin_amdgcn_mfma_f32_32x32x16_f16(af2, b12, acc[mi][1], 0, 0, 0); \
    acc[mi][0] = __builtin_amdgcn_mfma_f32_32x32x16_f16(af3, b03, acc[mi][0], 0, 0, 0); \
    acc[mi][1] = __builtin_amdgcn_mfma_f32_32x32x16_f16(af3, b13, acc[mi][1], 0, 0, 0);

// Phase: frag ds_reads | GLDS issues | barrier | 8 MFMA (compiler inserts
// progressive lgkmcnt per frag dependency) | [vmcnt gate] | barrier
#define PH(buf, mi, VW, ...) { \
    f16x8 af0 = *(const f16x8*)(aR + (buf) * TSZ + (mi) * 2048 + xs0); \
    f16x8 af1 = *(const f16x8*)(aR + (buf) * TSZ + (mi) * 2048 + xs1); \
    f16x8 af2 = *(const f16x8*)(aR + (buf) * TSZ + (mi) * 2048 + xs2); \
    f16x8 af3 = *(const f16x8*)(aR + (buf) * TSZ + (mi) * 2048 + xs3); \
    if ((mi) == 0) { \
        b00 = *(const f16x8*)(bR + (buf) * TSZ + xs0); \
        b01 = *(const f16x8*)(bR + (buf) * TSZ + xs1); \
        b02 = *(const f16x8*)(bR + (buf) * TSZ + xs2); \
        b03 = *(const f16x8*)(bR + (buf) * TSZ + xs3); \
        b10 = *(const f16x8*)(bR + (buf) * TSZ + 2048 + xs0); \
        b11 = *(const f16x8*)(bR + (buf) * TSZ + 2048 + xs1); \
        b12 = *(const f16x8*)(bR + (buf) * TSZ + 2048 + xs2); \
        b13 = *(const f16x8*)(bR + (buf) * TSZ + 2048 + xs3); \
    } \
    __VA_ARGS__ \
    __builtin_amdgcn_s_barrier(); \
    __builtin_amdgcn_s_setprio(1); \
    MFMA8(mi) \
    __builtin_amdgcn_s_setprio(0); \
    if (VW) { asm volatile("s_waitcnt vmcnt(6)" ::: "memory"); } \
    __builtin_amdgcn_s_barrier(); \
}

    for (int i = 0; i < NT / 2; ++i) {
        const long k1 = (long)(2 * i + 1) << 6;                           // tile t+1 (tail)
        const long kA = (2 * i + 2 < NT) ? ((long)(2 * i + 2) << 6) : 0;  // tile t+2
        const long kB = (2 * i + 3 < NT) ? ((long)(2 * i + 3) << 6) : 0;  // tile t+3
        PH(0, 0, 0, GAc(1,  64, k1); GAc(1, 192, k1);)
        PH(0, 1, 0, GBc(0,   0, kA); GBc(0,  64, kA);)
        PH(0, 2, 0, GBc(0, 128, kA); GBc(0, 192, kA);)
        PH(0, 3, 1, GAc(0,   0, kA); GAc(0, 128, kA);)
        PH(1, 0, 0, GAc(0,  64, kA); GAc(0, 192, kA);)
        PH(1, 1, 0, GBc(1,   0, kB); GBc(1,  64, kB);)
        PH(1, 2, 0, GBc(1, 128, kB); GBc(1, 192, kB);)
        PH(1, 3, 1, GAc(1,   0, kB); GAc(1, 128, kB);)
    }

    asm volatile("s_waitcnt vmcnt(0)" ::: "memory");    // drain before LDS dealloc

    // C/D layout (32x32): col = lane&31, row = (reg&3) + 8*(reg>>2) + 4*(lane>>5)
#pragma unroll
    for (int ni = 0; ni < 2; ++ni) {
        const int gc = n0 + wn + ni * 32 + lr;
        const float bv = BIAS ? bias[gc] : 0.0f;
#pragma unroll
        for (int mi = 0; mi < 4; ++mi) {
#pragma unroll
            for (int r = 0; r < 16; ++r) {
                const int row = (r & 3) + 8 * (r >> 2) + 4 * lh;
                const int gr = m0 + wm + mi * 32 + row;
                float v = acc[mi][ni][r] + bv;
                if (RELU) v = fmaxf(v, 0.0f);
                C[(long)gr * N + gc] = (OUT_T)v;
            }
        }
    }
#undef PH
#undef MFMA8
#undef GAc
#undef GBc
}

// ---------------------------------------------------------------------------
// Fused cast: proj_p -> pB (blocks [0,16384)), proj_q -> qB ([16384,32768)),
// W -> Wb ([32768, 33280)).  One launch instead of three.
__global__ __launch_bounds__(256)
void cast_all(const float* __restrict__ Xp, const float* __restrict__ Xq,
              const float* __restrict__ Xw, f16* __restrict__ Yp,
              f16* __restrict__ Yq, f16* __restrict__ Yw)
{
    const long b = blockIdx.x;
    const float* X;
    f16* Y;
    long off;
    if (b < 16384)      { X = Xp; Y = Yp; off = b; }
    else if (b < 32768) { X = Xq; Y = Yq; off = b - 16384; }
    else                { X = Xw; Y = Yw; off = b - 32768; }
    const long i = (off * 256 + threadIdx.x) * 8;
    float4 a = *(const float4*)(X + i);
    float4 c = *(const float4*)(X + i + 4);
    f16x8 h = {(f16)a.x, (f16)a.y, (f16)a.z, (f16)a.w,
               (f16)c.x, (f16)c.y, (f16)c.z, (f16)c.w};
    *(f16x8*)(Y + i) = h;
}

// f16 [2048 x 1024] per batch -> f16 [1024 x 2048] (LDS 64x64 tile transpose)
__global__ __launch_bounds__(256)
void trans_f16(const f16* __restrict__ X, f16* __restrict__ Y)
{
    __shared__ f16 t[64][72];
    const f16* Xb = X + (long)blockIdx.z * (2048L * 1024);
    f16* Yb = Y + (long)blockIdx.z * (1024L * 2048);
    const int r0 = blockIdx.y * 64;    // q
    const int c0 = blockIdx.x * 64;    // o
    const int tid = threadIdx.x;
    const int tr = tid >> 4;
    const int tc = (tid & 15) * 4;
#pragma unroll
    for (int rr = 0; rr < 64; rr += 16) {
        f16x4 v = *(const f16x4*)(Xb + (long)(r0 + tr + rr) * 1024 + c0 + tc);
        *(f16x4*)&t[tr + rr][tc] = v;
    }
    __syncthreads();
#pragma unroll
    for (int rr = 0; rr < 64; rr += 16) {
        const int orow = tr + rr;
        f16x4 o = {t[tc + 0][orow], t[tc + 1][orow], t[tc + 2][orow], t[tc + 3][orow]};
        *(f16x4*)(Yb + (long)(c0 + orow) * 2048 + r0 + tc) = o;
    }
}

// rowwise softmax over 2048 f16 scores -> fp16 probabilities
__global__ __launch_bounds__(256)
void softmax_ph(const f16* __restrict__ S, f16* __restrict__ P)
{
    const long row = blockIdx.x;
    const f16* s = S + row * 2048;
    f16* p = P + row * 2048;
    const int tid = threadIdx.x;
    const int wid = tid >> 6, lane = tid & 63;

    f16x8 hv = *(const f16x8*)(s + tid * 8);
    float v[8] = {(float)hv[0], (float)hv[1], (float)hv[2], (float)hv[3],
                  (float)hv[4], (float)hv[5], (float)hv[6], (float)hv[7]};

    float m = v[0];
#pragma unroll
    for (int j = 1; j < 8; ++j) m = fmaxf(m, v[j]);
#pragma unroll
    for (int off = 32; off > 0; off >>= 1) m = fmaxf(m, __shfl_xor(m, off, 64));

    __shared__ float red[8];
    if (lane == 0) red[wid] = m;
    __syncthreads();
    m = fmaxf(fmaxf(red[0], red[1]), fmaxf(red[2], red[3]));

    float sum = 0.f;
#pragma unroll
    for (int j = 0; j < 8; ++j) { v[j] = __expf(v[j] - m); sum += v[j]; }
#pragma unroll
    for (int off = 32; off > 0; off >>= 1) sum += __shfl_xor(sum, off, 64);
    if (lane == 0) red[4 + wid] = sum;
    __syncthreads();
    sum = red[4] + red[5] + red[6] + red[7];

    const float inv = 1.0f / sum;
    f16x8 h = {(f16)(v[0] * inv), (f16)(v[1] * inv), (f16)(v[2] * inv), (f16)(v[3] * inv),
               (f16)(v[4] * inv), (f16)(v[5] * inv), (f16)(v[6] * inv), (f16)(v[7] * inv)};
    *(f16x8*)(p + tid * 8) = h;
}

// ---------------------------------------------------------------------------
extern "C" void kernel_launch(void* const* d_in, const int* in_sizes, int n_in,
                              void* d_out, int out_size, void* d_ws, size_t ws_size,
                              hipStream_t stream)
{
    const float* proj_p = (const float*)d_in[0];  // [16,2048,1024]
    const float* proj_q = (const float*)d_in[1];  // [16,2048,1024]
    const float* W      = (const float*)d_in[2];  // [1024,1024]
    const float* bias   = (const float*)d_in[3];  // [1024]
    float* out = (float*)d_out;

    constexpr long Bc = 16, L = 2048, H = 1024;

    // Workspace layout (single-chunk, z=16 everywhere).  Liveness overlay:
    //   P (128 MB) overlays pB+qB — pB dead after G2, qB dead after G1,
    //   softmax (the writer of P) runs strictly after G2 on this stream.
    char* ws = (char*)d_ws;
    f16*   pB  = (f16*)(ws + 0L);                 // 67,108,864 B
    f16*   qB  = (f16*)(ws + 67108864L);          // 67,108,864 B
    f16*   tQ  = (f16*)(ws + 134217728L);         // 67,108,864 B  [B*L][H]
    f16*   tQt = (f16*)(ws + 201326592L);         // 67,108,864 B  [B][H][L]
    f16*   Wb  = (f16*)(ws + 268435456L);         //  2,097,152 B
    f16*   Sh  = (f16*)(ws + 270532608L);         // 134,217,728 B (16 batches f16)
    f16*   P   = (f16*)(ws + 0L);                 // 134,217,728 B (overlay pB+qB)

    // 1. all input casts in one launch
    cast_all<<<33280, 256, 0, stream>>>(proj_p, proj_q, W, pB, qB, Wb);

    // 2. G1: tQ[b,q,o] = qB[b,q,:] . Wb[o,:] + bias[o]   (256-tile 8-phase)
    gemm_bt2<f16, true, false><<<dim3(H / 256, (Bc * L) / 256, 1), 512, 0, stream>>>(
        qB, Wb, tQ, bias, (int)(Bc * L), (int)H, (int)H, 0, 0, 0);

    // 3. tQt[b][o][q] = tQ[b*L+q][o]
    trans_f16<<<dim3(16, 32, 16), 256, 0, stream>>>(tQ, tQt);

    // 4. G2: Sh[b][p,q] = pB[b][p,:] . tQ[b][q,:]   (f16 out, all 16 batches)
    gemm_bt2<f16, false, false><<<dim3(L / 256, L / 256, (int)Bc), 512, 0, stream>>>(
        pB, tQ, Sh, nullptr, (int)L, (int)L, (int)H, L * H, L * H, L * L);

    // 5. softmax rows (f16 in) -> P f16   (P overlays pB/qB — both dead now)
    softmax_ph<<<(int)(Bc * L), 256, 0, stream>>>(Sh, P);

    // 6. G3': out[b][p,o] = relu( P[b][p,:] . tQt[b][o,:] )
    //    z=16 makes the 256x256 grid 4x8x16 = 512 blocks = 2 full rounds,
    //    so the proven 808-TF gemm_bt2 replaces the 605-TF 256x128 variant.
    gemm_bt2<float, false, true><<<dim3(H / 256, L / 256, (int)Bc), 512, 0, stream>>>(
        P, tQt, out, nullptr, (int)L, (int)H, (int)L, L * L, H * L, L * H);
}